// Round 1
// baseline (15707.626 us; speedup 1.0000x reference)
//
#include <hip/hip_runtime.h>
#include <hip/hip_bf16.h>

#define DEVINL __device__ __forceinline__

typedef __bf16 bf16_t;
typedef __bf16 bf16x8 __attribute__((ext_vector_type(8)));
typedef float  f32x4  __attribute__((ext_vector_type(4)));

static constexpr int SEQ  = 512;   // sequence length
static constexpr int BT   = 16;    // batch rows per block (= MFMA M)
static constexpr int PSTR = 128;   // activation plane inner stride (elems)
static constexpr int GSTR = 516;   // gate LDS row stride in words (512+4 pad -> 2-way max)

DEVINL f32x4 mfma16(bf16x8 a, bf16x8 b, f32x4 c) {
  return __builtin_amdgcn_mfma_f32_16x16x32_bf16(a, b, c, 0, 0, 0);
}

DEVINL float fast_sigmoid(float x) {
  float e = __builtin_amdgcn_exp2f(-1.442695040888963f * x);
  return __builtin_amdgcn_rcpf(1.0f + e);
}
DEVINL float fast_tanh(float x) {
  x = fminf(40.0f, fmaxf(-40.0f, x));           // keep exp2 finite
  float e = __builtin_amdgcn_exp2f(-2.885390081777927f * x); // exp(-2x)
  return (1.0f - e) * __builtin_amdgcn_rcpf(1.0f + e);
}

// One LSTM layer for this block's 16-row batch tile, all 512 steps.
// XMODE 0: x = input_seq fp32 (B,S,8). XMODE 1: x = bf16 hi/lo planes, stride PSTR.
// Gate matmul: [x_t, h] (M=16, K=LIN+H) @ [Wih;Whh]^T (K x 4H), split-bf16 (3 MFMAs/term).
template<int LIN, int H, int XMODE, bool WOUT, bool LAST>
DEVINL void run_layer(
    const float* __restrict__ wih, const float* __restrict__ whh,
    const float* __restrict__ bih, const float* __restrict__ bhh,
    const float* x0,
    const bf16_t* xhi, const bf16_t* xlo,
    bf16_t* ohi, bf16_t* olo,
    int b0, int use_lo,
    float (&g_lds)[BT*GSTR],
    bf16_t (&hbh)[BT*128], bf16_t (&hbl)[BT*128],
    float (&h_fin)[BT*64])
{
  constexpr int N4H = 4*H;
  constexpr int NT  = N4H/16;                 // 16-wide gate tiles
  constexpr int TPW = NT/16;                  // tiles per wave (16 waves)
  constexpr int KX  = (XMODE==0) ? 1 : LIN/32;
  constexpr int KH  = H/32;
  constexpr int KT  = KX + KH;

  const int tid = (int)threadIdx.x;
  const int wv  = tid >> 6;    // wave id 0..15
  const int ln  = tid & 63;    // lane
  const int lr  = ln & 15;     // A: M-row / B,D: N-col
  const int lg  = ln >> 4;     // k-group

  // ---- weight fragments: B[k][n], lane holds n=Nbase+lr, k=kt*32+lg*8+i ----
  bf16x8 wfh[TPW][KT], wfl[TPW][KT];
  float biasv[TPW];
  #pragma unroll
  for (int tp = 0; tp < TPW; ++tp) {
    const int n = (wv*TPW + tp)*16 + lr;
    biasv[tp] = bih[n] + bhh[n];
    #pragma unroll
    for (int kt = 0; kt < KT; ++kt) {
      #pragma unroll
      for (int i = 0; i < 8; ++i) {
        float v;
        if (kt < KX) {
          int k = kt*32 + lg*8 + i;
          v = (k < LIN) ? wih[n*LIN + k] : 0.0f;   // L0 pads K 8->32
        } else {
          int k = (kt-KX)*32 + lg*8 + i;
          v = whh[n*H + k];
        }
        bf16_t hh = (bf16_t)v;
        wfh[tp][kt][i] = hh;
        wfl[tp][kt][i] = (bf16_t)(v - (float)hh);
      }
    }
  }

  // ---- zero h state ----
  for (int z = tid; z < BT*128; z += 1024) {
    hbh[z] = (bf16_t)0.0f; hbl[z] = (bf16_t)0.0f;
  }
  float c0 = 0.0f, c1 = 0.0f;
  __syncthreads();

  // x A-fragments: row=lr, k=kt*32+lg*8+i
  auto LOAD_X = [&](int t, bf16x8 (&xh)[KX], bf16x8 (&xl)[KX]) {
    if (XMODE == 0) {
      #pragma unroll
      for (int i = 0; i < 8; ++i) { xh[0][i] = (bf16_t)0.0f; xl[0][i] = (bf16_t)0.0f; }
      if (lg == 0) {
        const float* p = x0 + ((size_t)(b0+lr)*SEQ + t)*8;
        #pragma unroll
        for (int i = 0; i < 8; ++i) {
          float v = p[i];
          bf16_t hh = (bf16_t)v;
          xh[0][i] = hh;
          xl[0][i] = (bf16_t)(v - (float)hh);
        }
      }
    } else {
      size_t base = ((size_t)(b0+lr)*SEQ + t)*PSTR + lg*8;
      #pragma unroll
      for (int kt = 0; kt < KX; ++kt) {
        xh[kt] = *(const bf16x8*)(xhi + base + kt*32);
        if (use_lo) {
          xl[kt] = *(const bf16x8*)(xlo + base + kt*32);
        } else {
          #pragma unroll
          for (int i = 0; i < 8; ++i) xl[kt][i] = (bf16_t)0.0f;
        }
      }
    }
  };

  auto STEP = [&](int t, bf16x8 (&xh)[KX], bf16x8 (&xl)[KX],
                  bf16x8 (&nxh)[KX], bf16x8 (&nxl)[KX]) {
    // prefetch next step's x fragments (hidden under MFMA+gates)
    int tn = (t+1 < SEQ) ? (t+1) : (SEQ-1);
    LOAD_X(tn, nxh, nxl);

    // h_{t-1} A-fragments from swizzled LDS (conflict-free ds_read_b128)
    bf16x8 ahh[KH], ahl[KH];
    #pragma unroll
    for (int kt = 0; kt < KH; ++kt) {
      int k0 = kt*32 + lg*8;
      int idx = lr*H + (k0 ^ ((lr & 7) << 3));
      ahh[kt] = *(const bf16x8*)&hbh[idx];
      ahl[kt] = *(const bf16x8*)&hbl[idx];
    }

    // gate preacts = bias + x-path + h-path, split-bf16 (hi*hi + hi*lo + lo*hi)
    f32x4 acc[TPW];
    #pragma unroll
    for (int tp = 0; tp < TPW; ++tp) {
      f32x4 a = {biasv[tp], biasv[tp], biasv[tp], biasv[tp]};
      #pragma unroll
      for (int kt = 0; kt < KX; ++kt) {
        a = mfma16(xh[kt], wfh[tp][kt], a);
        a = mfma16(xh[kt], wfl[tp][kt], a);
        a = mfma16(xl[kt], wfh[tp][kt], a);
      }
      #pragma unroll
      for (int kt = 0; kt < KH; ++kt) {
        a = mfma16(ahh[kt], wfh[tp][KX+kt], a);
        a = mfma16(ahh[kt], wfl[tp][KX+kt], a);
        a = mfma16(ahl[kt], wfh[tp][KX+kt], a);
      }
      acc[tp] = a;
    }

    // D layout: col = lr, row = lg*4 + r  -> scatter to gate LDS
    #pragma unroll
    for (int tp = 0; tp < TPW; ++tp) {
      const int n = (wv*TPW + tp)*16 + lr;
      #pragma unroll
      for (int r = 0; r < 4; ++r)
        g_lds[(lg*4 + r)*GSTR + n] = acc[tp][r];
    }
    __syncthreads();

    // gate phase: wave wv owns batch row wv; lane covers j = ln (+64)
    {
      const int b = wv;
      const float* gr = &g_lds[b*GSTR];
      #pragma unroll
      for (int e = 0; e < (H == 128 ? 2 : 1); ++e) {
        const int j = ln + e*64;
        float gi = gr[j];
        float gf = gr[j + H];
        float gg = gr[j + 2*H];
        float go = gr[j + 3*H];
        float iv = fast_sigmoid(gi);
        float fv = fast_sigmoid(gf);
        float gv = fast_tanh(gg);
        float ov = fast_sigmoid(go);
        float& c = (e == 0) ? c0 : c1;
        c = fv*c + iv*gv;
        float h = ov * fast_tanh(c);
        bf16_t hh = (bf16_t)h;
        bf16_t hl = (bf16_t)(h - (float)hh);
        int sidx = b*H + (j ^ ((b & 7) << 3));
        hbh[sidx] = hh; hbl[sidx] = hl;
        if (WOUT) {
          size_t off = ((size_t)(b0+b)*SEQ + t)*PSTR + j;
          ohi[off] = hh;
          if (use_lo) olo[off] = hl;
        }
        if (LAST && t == SEQ-1) h_fin[b*64 + j] = h;
      }
    }
    __syncthreads();
  };

  bf16x8 xhA[KX], xlA[KX], xhB[KX], xlB[KX];
  LOAD_X(0, xhA, xlA);
  for (int t = 0; t < SEQ; t += 2) {
    STEP(t,   xhA, xlA, xhB, xlB);
    STEP(t+1, xhB, xlB, xhA, xlA);
  }
}

extern "C" __global__ __launch_bounds__(1024, 1)
void lstm_fused(const float* __restrict__ xin,
  const float* w0i, const float* w0h, const float* b0i, const float* b0h,
  const float* w1i, const float* w1h, const float* b1i, const float* b1h,
  const float* w2i, const float* w2h, const float* b2i, const float* b2h,
  const float* w3i, const float* w3h, const float* b3i, const float* b3h,
  const float* __restrict__ lw, const float* __restrict__ lb,
  float* __restrict__ out,
  bf16_t* ph, bf16_t* pl, int use_lo)
{
  __shared__ float g_lds[BT*GSTR];
  __shared__ __align__(16) bf16_t hbh[BT*128];
  __shared__ __align__(16) bf16_t hbl[BT*128];
  __shared__ float h_fin[BT*64];

  const int b0 = (int)blockIdx.x * BT;

  // L0: 8 -> 128, reads fp32 input_seq, writes hi/lo planes
  run_layer<8,   128, 0, true,  false>(w0i,w0h,b0i,b0h, xin, nullptr,nullptr,
                                       ph,pl, b0,use_lo, g_lds,hbh,hbl,h_fin);
  __syncthreads();
  // L1: 128 -> 128, in-place on planes (slot t consumed before overwritten)
  run_layer<128, 128, 1, true,  false>(w1i,w1h,b1i,b1h, nullptr, ph,pl,
                                       ph,pl, b0,use_lo, g_lds,hbh,hbl,h_fin);
  __syncthreads();
  // L2: 128 -> 64, writes first 64 cols of each slot in-place
  run_layer<128, 64,  1, true,  false>(w2i,w2h,b2i,b2h, nullptr, ph,pl,
                                       ph,pl, b0,use_lo, g_lds,hbh,hbl,h_fin);
  __syncthreads();
  // L3: 64 -> 64, no sequence output; final h kept fp32 in LDS
  run_layer<64,  64,  1, false, true >(w3i,w3h,b3i,b3h, nullptr, ph,pl,
                                       nullptr,nullptr, b0,use_lo, g_lds,hbh,hbl,h_fin);

  // final linear: out[b] = h_fin[b,:] . lw + lb   (wave wv handles row wv)
  const int wv = (int)threadIdx.x >> 6;
  const int ln = (int)threadIdx.x & 63;
  float v = h_fin[wv*64 + ln] * lw[ln];
  #pragma unroll
  for (int m = 32; m >= 1; m >>= 1) v += __shfl_xor(v, m, 64);
  if (ln == 0) out[b0 + wv] = v + lb[0];
}

extern "C" void kernel_launch(void* const* d_in, const int* in_sizes, int n_in,
                              void* d_out, int out_size, void* d_ws, size_t ws_size,
                              hipStream_t stream) {
  const float* xin = (const float*)d_in[0];
  const float* w0i = (const float*)d_in[1];
  const float* w0h = (const float*)d_in[2];
  const float* b0i = (const float*)d_in[3];
  const float* b0h = (const float*)d_in[4];
  const float* w1i = (const float*)d_in[5];
  const float* w1h = (const float*)d_in[6];
  const float* b1i = (const float*)d_in[7];
  const float* b1h = (const float*)d_in[8];
  const float* w2i = (const float*)d_in[9];
  const float* w2h = (const float*)d_in[10];
  const float* b2i = (const float*)d_in[11];
  const float* b2h = (const float*)d_in[12];
  const float* w3i = (const float*)d_in[13];
  const float* w3h = (const float*)d_in[14];
  const float* b3i = (const float*)d_in[15];
  const float* b3h = (const float*)d_in[16];
  const float* lw  = (const float*)d_in[17];
  const float* lb  = (const float*)d_in[18];
  float* out = (float*)d_out;

  const size_t plane = (size_t)1024 * 512 * 128;       // elems per plane
  bf16_t* ph = (bf16_t*)d_ws;
  int use_lo = (ws_size >= plane * 2 * sizeof(bf16_t)) ? 1 : 0;
  bf16_t* pl = use_lo ? (ph + plane) : ph;             // pl unused when !use_lo

  lstm_fused<<<64, 1024, 0, stream>>>(xin,
      w0i,w0h,b0i,b0h, w1i,w1h,b1i,b1h, w2i,w2h,b2i,b2h, w3i,w3h,b3i,b3h,
      lw, lb, out, ph, pl, use_lo);
}

// Round 2
// 2614.044 us; speedup vs baseline: 6.0089x; 6.0089x over previous
//
#include <hip/hip_runtime.h>

#define DEVINL __device__ __forceinline__

typedef _Float16 f16_t;
typedef _Float16 f16x8 __attribute__((ext_vector_type(8)));
typedef float    f32x4 __attribute__((ext_vector_type(4)));

static constexpr int SEQ  = 512;   // sequence length
static constexpr int BT   = 16;    // batch rows per block (= MFMA M)
static constexpr int PSTR = 128;   // activation plane inner stride (elems)
static constexpr int GSTR = 516;   // gate LDS row stride in floats (512+4 pad -> 2-way max)
static constexpr int NW   = 8;     // waves per block

DEVINL f32x4 mfma16(f16x8 a, f16x8 b, f32x4 c) {
  return __builtin_amdgcn_mfma_f32_16x16x32_f16(a, b, c, 0, 0, 0);
}

DEVINL float fast_sigmoid(float x) {
  float e = __builtin_amdgcn_exp2f(-1.442695040888963f * x);
  return __builtin_amdgcn_rcpf(1.0f + e);
}
DEVINL float fast_tanh(float x) {
  x = fminf(40.0f, fmaxf(-40.0f, x));           // keep exp2 finite
  float e = __builtin_amdgcn_exp2f(-2.885390081777927f * x); // exp(-2x)
  return (1.0f - e) * __builtin_amdgcn_rcpf(1.0f + e);
}

// lgkmcnt-only barrier: LDS producer/consumer sync WITHOUT draining vmcnt,
// so global prefetch loads / output stores stay in flight across steps.
DEVINL void sync_raw() {
  asm volatile("s_waitcnt lgkmcnt(0)" ::: "memory");
  __builtin_amdgcn_s_barrier();
  asm volatile("" ::: "memory");
}

// One LSTM layer for this block's 16-row batch tile, all 512 steps.
// XMODE 0: x = input_seq fp32 (B,S,8), K padded 8->32, split hi/lo on the fly.
// XMODE 1: x = fp16 hi-only plane (stride PSTR), per-wave register prefetch.
// Weights: fp16 hi-only in registers (B-fragments). h: split fp16 hi+lo in LDS.
template<int LIN, int H, int XMODE, bool WOUT, bool LAST>
DEVINL void run_layer(const float* __restrict__ wih, const float* __restrict__ whh,
                      const float* __restrict__ bih, const float* __restrict__ bhh,
                      const float* __restrict__ x0,
                      const f16_t* __restrict__ xpl, f16_t* __restrict__ opl,
                      int b0,
                      float* g_lds, f16_t* hbh, f16_t* hbl, float* h_fin)
{
  constexpr int NT   = 4*H/16;                 // 16-wide gate tiles
  constexpr int TPW  = NT/NW;                  // tiles per wave
  constexpr int KX   = (XMODE==0) ? 1 : LIN/32;
  constexpr int KH   = H/32;
  constexpr int ROWS = BT/NW;                  // batch rows per wave in gate phase (2)
  constexpr int NE   = H/64;                   // gate cols per row per lane

  const int tid = (int)threadIdx.x;
  const int wv = tid >> 6, ln = tid & 63, lr = ln & 15, lg = ln >> 4;

  // ---- weight B-fragments: lane holds col n, k = kt*32 + lg*8 + i ----
  f16x8 wf[TPW][KX+KH];
  float biasv[TPW];
  #pragma unroll
  for (int tp = 0; tp < TPW; ++tp) {
    const int n = (wv*TPW + tp)*16 + lr;
    biasv[tp] = bih[n] + bhh[n];
    #pragma unroll
    for (int kt = 0; kt < KX; ++kt) {
      #pragma unroll
      for (int i = 0; i < 8; ++i) {
        const int k = kt*32 + lg*8 + i;
        wf[tp][kt][i] = (f16_t)((k < LIN) ? wih[n*LIN + k] : 0.0f);  // L0 pads 8->32
      }
    }
    #pragma unroll
    for (int kt = 0; kt < KH; ++kt) {
      #pragma unroll
      for (int i = 0; i < 8; ++i) {
        const int k = kt*32 + lg*8 + i;
        wf[tp][KX+kt][i] = (f16_t)whh[n*H + k];
      }
    }
  }

  // ---- zero h state ----
  for (int z = tid; z < BT*H; z += NW*64) { hbh[z] = (f16_t)0.0f; hbl[z] = (f16_t)0.0f; }
  float cst[ROWS][NE];
  #pragma unroll
  for (int rr = 0; rr < ROWS; ++rr)
    #pragma unroll
    for (int e = 0; e < NE; ++e) cst[rr][e] = 0.0f;
  __syncthreads();

  // ---- x prefetch (registers, distance 1) ----
  f16x8 xA[KX], xB[KX];
  float pA[8] = {}, pB[8] = {};

  auto loadx = [&](int t, f16x8 (&xr)[KX], float (&pr)[8]) {
    if constexpr (XMODE == 0) {
      if (lg == 0) {
        const float* p = x0 + ((size_t)(b0+lr)*SEQ + t)*8;
        #pragma unroll
        for (int i = 0; i < 8; ++i) pr[i] = p[i];
      }
    } else {
      const f16_t* p = xpl + ((size_t)(b0+lr)*SEQ + t)*PSTR + lg*8;
      #pragma unroll
      for (int kt = 0; kt < KX; ++kt) xr[kt] = *(const f16x8*)(p + kt*32);
    }
  };

  auto step = [&](int t, f16x8 (&xc)[KX], float (&pc)[8],
                         f16x8 (&xn)[KX], float (&pn)[8]) {
    const int tn = (t+1 < SEQ) ? t+1 : SEQ-1;

    f32x4 acc[TPW];
    #pragma unroll
    for (int tp = 0; tp < TPW; ++tp) {
      f32x4 a = {biasv[tp], biasv[tp], biasv[tp], biasv[tp]};
      acc[tp] = a;
    }

    if constexpr (XMODE == 0) {
      f16x8 xh, xl;
      #pragma unroll
      for (int i = 0; i < 8; ++i) {
        const float v = (lg == 0) ? pc[i] : 0.0f;
        const f16_t hi = (f16_t)v;
        xh[i] = hi; xl[i] = (f16_t)(v - (float)hi);
      }
      loadx(tn, xn, pn);                      // prefetch t+1
      #pragma unroll
      for (int tp = 0; tp < TPW; ++tp) {
        acc[tp] = mfma16(xh, wf[tp][0], acc[tp]);
        acc[tp] = mfma16(xl, wf[tp][0], acc[tp]);
      }
    } else {
      loadx(tn, xn, pn);                      // prefetch t+1
      #pragma unroll
      for (int kt = 0; kt < KX; ++kt)
        #pragma unroll
        for (int tp = 0; tp < TPW; ++tp)
          acc[tp] = mfma16(xc[kt], wf[tp][kt], acc[tp]);
    }

    // h terms from swizzled LDS (split hi+lo)
    #pragma unroll
    for (int kt = 0; kt < KH; ++kt) {
      const int chunk = ((kt*4 + lg) ^ (lr & 7)) * 8;
      f16x8 hh = *(const f16x8*)&hbh[lr*H + chunk];
      f16x8 hl = *(const f16x8*)&hbl[lr*H + chunk];
      #pragma unroll
      for (int tp = 0; tp < TPW; ++tp) {
        acc[tp] = mfma16(hh, wf[tp][KX+kt], acc[tp]);
        acc[tp] = mfma16(hl, wf[tp][KX+kt], acc[tp]);
      }
    }

    // D layout: col = lr, row(batch) = lg*4 + r -> scatter preacts to gate LDS
    #pragma unroll
    for (int tp = 0; tp < TPW; ++tp) {
      const int n = (wv*TPW + tp)*16 + lr;
      #pragma unroll
      for (int r = 0; r < 4; ++r)
        g_lds[(lg*4 + r)*GSTR + n] = acc[tp][r];
    }
    sync_raw();

    // gate phase: wave wv owns batch rows 2wv, 2wv+1
    #pragma unroll
    for (int rr = 0; rr < ROWS; ++rr) {
      const int b = wv*ROWS + rr;
      const float* gr = g_lds + b*GSTR;
      #pragma unroll
      for (int e = 0; e < NE; ++e) {
        const int j = ln + e*64;
        const float gi = gr[j], gf = gr[j+H], gg = gr[j+2*H], go = gr[j+3*H];
        const float iv = fast_sigmoid(gi);
        const float fv = fast_sigmoid(gf);
        const float gv = fast_tanh(gg);
        const float ov = fast_sigmoid(go);
        const float cv = fv*cst[rr][e] + iv*gv;
        cst[rr][e] = cv;
        const float h = ov * fast_tanh(cv);
        const f16_t hh = (f16_t)h;
        const f16_t hl = (f16_t)(h - (float)hh);
        const int sidx = b*H + (j ^ ((b & 7) << 3));
        hbh[sidx] = hh; hbl[sidx] = hl;
        if constexpr (WOUT)
          opl[((size_t)(b0+b)*SEQ + t)*PSTR + j] = hh;
        if constexpr (LAST)
          if (t == SEQ-1) h_fin[b*64 + j] = h;
      }
    }
    sync_raw();
  };

  loadx(0, xA, pA);
  for (int t = 0; t < SEQ; t += 2) {
    step(t,   xA, pA, xB, pB);
    step(t+1, xB, pB, xA, pA);
  }
}

extern "C" __global__ __launch_bounds__(512, 2)
void lstm_fused(const float* __restrict__ xin,
  const float* w0i, const float* w0h, const float* b0i, const float* b0h,
  const float* w1i, const float* w1h, const float* b1i, const float* b1h,
  const float* w2i, const float* w2h, const float* b2i, const float* b2h,
  const float* w3i, const float* w3h, const float* b3i, const float* b3h,
  const float* __restrict__ lw, const float* __restrict__ lb,
  float* __restrict__ out, f16_t* plane)
{
  __shared__ float g_lds[BT*GSTR];              // 33 KB
  __shared__ __align__(16) f16_t hbh[BT*128];   // 4 KB
  __shared__ __align__(16) f16_t hbl[BT*128];   // 4 KB
  __shared__ float h_fin[BT*64];                // 4 KB

  const int b0 = (int)blockIdx.x * BT;

  // L0: 8 -> 128, fp32 input, writes fp16 hi plane
  run_layer<8,   128, 0, true,  false>(w0i,w0h,b0i,b0h, xin, nullptr, plane,
                                       b0, g_lds,hbh,hbl,h_fin);
  asm volatile("s_waitcnt vmcnt(0) lgkmcnt(0)" ::: "memory");
  __syncthreads();
  // L1: 128 -> 128, in-place on plane (slot t consumed before overwritten)
  run_layer<128, 128, 1, true,  false>(w1i,w1h,b1i,b1h, nullptr, plane, plane,
                                       b0, g_lds,hbh,hbl,h_fin);
  asm volatile("s_waitcnt vmcnt(0) lgkmcnt(0)" ::: "memory");
  __syncthreads();
  // L2: 128 -> 64, writes first 64 cols of each slot in-place
  run_layer<128, 64,  1, true,  false>(w2i,w2h,b2i,b2h, nullptr, plane, plane,
                                       b0, g_lds,hbh,hbl,h_fin);
  asm volatile("s_waitcnt vmcnt(0) lgkmcnt(0)" ::: "memory");
  __syncthreads();
  // L3: 64 -> 64, no sequence output; final h kept fp32 in LDS
  run_layer<64,  64,  1, false, true >(w3i,w3h,b3i,b3h, nullptr, plane, nullptr,
                                       b0, g_lds,hbh,hbl,h_fin);

  // final linear: out[b] = h_fin[b,:] . lw + lb
  const int wv = (int)threadIdx.x >> 6;
  const int ln = (int)threadIdx.x & 63;
  #pragma unroll
  for (int rr = 0; rr < 2; ++rr) {
    const int row = wv*2 + rr;
    float v = h_fin[row*64 + ln] * lw[ln];
    #pragma unroll
    for (int m = 32; m >= 1; m >>= 1) v += __shfl_xor(v, m, 64);
    if (ln == 0) out[b0 + row] = v + lb[0];
  }
}

extern "C" void kernel_launch(void* const* d_in, const int* in_sizes, int n_in,
                              void* d_out, int out_size, void* d_ws, size_t ws_size,
                              hipStream_t stream) {
  const float* xin = (const float*)d_in[0];
  const float* w0i = (const float*)d_in[1];
  const float* w0h = (const float*)d_in[2];
  const float* b0i = (const float*)d_in[3];
  const float* b0h = (const float*)d_in[4];
  const float* w1i = (const float*)d_in[5];
  const float* w1h = (const float*)d_in[6];
  const float* b1i = (const float*)d_in[7];
  const float* b1h = (const float*)d_in[8];
  const float* w2i = (const float*)d_in[9];
  const float* w2h = (const float*)d_in[10];
  const float* b2i = (const float*)d_in[11];
  const float* b2h = (const float*)d_in[12];
  const float* w3i = (const float*)d_in[13];
  const float* w3h = (const float*)d_in[14];
  const float* b3i = (const float*)d_in[15];
  const float* b3h = (const float*)d_in[16];
  const float* lw  = (const float*)d_in[17];
  const float* lb  = (const float*)d_in[18];
  float* out = (float*)d_out;
  f16_t* plane = (f16_t*)d_ws;   // 1024*512*128 fp16 = 134 MB

  lstm_fused<<<64, 512, 0, stream>>>(xin,
      w0i,w0h,b0i,b0h, w1i,w1h,b1i,b1h, w2i,w2h,b2i,b2h, w3i,w3h,b3i,b3h,
      lw, lb, out, plane);
}

// Round 3
// 1747.647 us; speedup vs baseline: 8.9879x; 1.4958x over previous
//
#include <hip/hip_runtime.h>

#define DEVINL __device__ __forceinline__

typedef _Float16 f16_t;
typedef _Float16 f16x8 __attribute__((ext_vector_type(8)));
typedef float    f32x4 __attribute__((ext_vector_type(4)));

static constexpr int SEQ  = 512;   // sequence length
static constexpr int BT   = 16;    // batch rows per block (= MFMA M)
static constexpr int PSTR = 128;   // activation plane inner stride (elems)
static constexpr int NW   = 8;     // waves per block

DEVINL f32x4 mfma16(f16x8 a, f16x8 b, f32x4 c) {
  return __builtin_amdgcn_mfma_f32_16x16x32_f16(a, b, c, 0, 0, 0);
}

DEVINL float fast_sigmoid(float x) {
  float e = __builtin_amdgcn_exp2f(-1.442695040888963f * x);
  return __builtin_amdgcn_rcpf(1.0f + e);
}
DEVINL float fast_tanh(float x) {
  x = fminf(40.0f, fmaxf(-40.0f, x));           // keep exp2 finite
  float e = __builtin_amdgcn_exp2f(-2.885390081777927f * x); // exp(-2x)
  return (1.0f - e) * __builtin_amdgcn_rcpf(1.0f + e);
}

// lgkmcnt-only barrier: LDS producer/consumer sync WITHOUT draining vmcnt,
// so global prefetch loads / plane stores stay in flight across steps.
DEVINL void sync_raw() {
  asm volatile("s_waitcnt lgkmcnt(0)" ::: "memory");
  __builtin_amdgcn_s_barrier();
  asm volatile("" ::: "memory");
}

// One LSTM layer for this block's 16-row batch tile, all 512 steps.
//
// In-register gate scheme: wave wv owns hidden-col slice j in [wv*16, wv*16+16)
// and computes ALL FOUR gate tiles {g*H + slice : g=0..3}. MFMA D layout
// (col=lane&15, row=(lane>>4)*4+r) puts gates i,f,g,o for batch row lg*4+r,
// col j into acc[0..3][r] of one lane -> gates + c-state fully in registers,
// h written straight to (double-buffered, XOR-swizzled) LDS. ONE barrier/step.
//
// Pipeline per step t (acc holds bias + x_t path on entry; xc holds x_{t+1}):
//   h-MFMAs (read h_{t-1} from LDS) -> prefetch x_{t+2} -> acc2 = bias + x_{t+1}
//   MFMAs (fills matrix pipe) -> gate VALU (under x-MFMA shadow) -> h write -> barrier.
template<int LIN, int H, int XMODE, bool WOUT, bool LAST>
DEVINL void run_layer(const float* __restrict__ wih, const float* __restrict__ whh,
                      const float* __restrict__ bih, const float* __restrict__ bhh,
                      const float* __restrict__ x0,
                      const f16_t* __restrict__ xpl, f16_t* __restrict__ opl,
                      int b0,
                      f16_t* hbA, f16_t* hbB, float* h_fin)
{
  constexpr int H16 = H/16;                    // col slices (= active waves)
  constexpr int KX  = (XMODE==0) ? 1 : LIN/32; // x-path K tiles
  constexpr int KH  = H/32;                    // h-path K tiles

  const int tid = (int)threadIdx.x;
  const int wv = tid >> 6, ln = tid & 63, lr = ln & 15, lg = ln >> 4;
  const bool act = (wv < H16);                 // wave-uniform
  const int j = wv*16 + lr;                    // this lane's hidden col

  // ---- weight B-fragments: wf[g][kt], lane holds col n=g*H+j, k=kt*32+lg*8+i ----
  f16x8 wf[4][KX+KH];
  float bias4[4];
  if (act) {
    #pragma unroll
    for (int g = 0; g < 4; ++g) {
      const int n = g*H + j;
      bias4[g] = bih[n] + bhh[n];
      #pragma unroll
      for (int kt = 0; kt < KX; ++kt)
        #pragma unroll
        for (int i = 0; i < 8; ++i) {
          const int k = kt*32 + lg*8 + i;
          wf[g][kt][i] = (f16_t)((k < LIN) ? wih[n*LIN + k] : 0.0f);  // L0 pads 8->32
        }
      #pragma unroll
      for (int kt = 0; kt < KH; ++kt)
        #pragma unroll
        for (int i = 0; i < 8; ++i)
          wf[g][KX+kt][i] = (f16_t)whh[n*H + kt*32 + lg*8 + i];
    }
  }

  // ---- zero both h buffers ----
  for (int z = tid; z < BT*H; z += NW*64) { hbA[z] = (f16_t)0.0f; hbB[z] = (f16_t)0.0f; }
  float c4[4] = {0.0f, 0.0f, 0.0f, 0.0f};

  auto loadx = [&](int t, f16x8 (&xr)[KX]) {
    if constexpr (XMODE == 0) {
      if (lg == 0) {
        const float* p = x0 + ((size_t)(b0+lr)*SEQ + t)*8;
        #pragma unroll
        for (int i = 0; i < 8; ++i) xr[0][i] = (f16_t)p[i];
      } else {
        #pragma unroll
        for (int i = 0; i < 8; ++i) xr[0][i] = (f16_t)0.0f;
      }
    } else {
      const f16_t* p = xpl + ((size_t)(b0+lr)*SEQ + t)*PSTR + lg*8;
      #pragma unroll
      for (int kt = 0; kt < KX; ++kt) xr[kt] = *(const f16x8*)(p + kt*32);
    }
  };

  // ---- prologue: acc = bias + x_0 path; xc = x_1 ----
  f32x4 accA[4], accB[4];
  f16x8 xA[KX], xB[KX];
  if (act) {
    f16x8 xr0[KX];
    loadx(0, xr0);
    #pragma unroll
    for (int g = 0; g < 4; ++g) {
      f32x4 a = {bias4[g], bias4[g], bias4[g], bias4[g]};
      accA[g] = a;
    }
    #pragma unroll
    for (int kt = 0; kt < KX; ++kt)
      #pragma unroll
      for (int g = 0; g < 4; ++g) accA[g] = mfma16(xr0[kt], wf[g][kt], accA[g]);
    loadx(1, xA);
  }
  __syncthreads();

  auto step = [&](int t, f32x4 (&ac)[4], f32x4 (&an)[4],
                         f16x8 (&xc)[KX], f16x8 (&xn)[KX],
                         f16_t* hr, f16_t* hw) {
    if (act) {
      // h-path MFMAs: h_{t-1} A-frags from swizzled LDS (conflict-free b128)
      #pragma unroll
      for (int kt = 0; kt < KH; ++kt) {
        const int chunk = ((kt*4 + lg) ^ (lr & 7)) * 8;
        const f16x8 ah = *(const f16x8*)&hr[lr*H + chunk];
        #pragma unroll
        for (int g = 0; g < 4; ++g) ac[g] = mfma16(ah, wf[g][KX+kt], ac[g]);
      }

      // prefetch x_{t+2} (consumed next step; overwrite of slot happens 2 barriers later)
      const int tf = (t+2 < SEQ) ? t+2 : SEQ-1;
      loadx(tf, xn);

      // next-step accumulator: bias + x_{t+1} path (independent of h_t -> fills pipe)
      #pragma unroll
      for (int g = 0; g < 4; ++g) {
        f32x4 a = {bias4[g], bias4[g], bias4[g], bias4[g]};
        an[g] = a;
      }
      #pragma unroll
      for (int kt = 0; kt < KX; ++kt)
        #pragma unroll
        for (int g = 0; g < 4; ++g) an[g] = mfma16(xc[kt], wf[g][kt], an[g]);

      // gates: fully in-register; c lives in c4[]
      #pragma unroll
      for (int r = 0; r < 4; ++r) {
        const int b = lg*4 + r;
        const float iv = fast_sigmoid(ac[0][r]);
        const float fv = fast_sigmoid(ac[1][r]);
        const float gv = fast_tanh(ac[2][r]);
        const float ov = fast_sigmoid(ac[3][r]);
        c4[r] = fv*c4[r] + iv*gv;
        const float h = ov * fast_tanh(c4[r]);
        hw[b*H + (j ^ ((b & 7) << 3))] = (f16_t)h;
        if constexpr (WOUT)
          opl[((size_t)(b0+b)*SEQ + t)*PSTR + j] = (f16_t)h;
        if constexpr (LAST)
          if (t == SEQ-1) h_fin[b*64 + j] = h;
      }
    }
    sync_raw();
  };

  for (int t = 0; t < SEQ; t += 2) {
    step(t,   accA, accB, xA, xB, hbB, hbA);   // even t: read hbB (h_{t-1}), write hbA
    step(t+1, accB, accA, xB, xA, hbA, hbB);   // odd  t: read hbA,            write hbB
  }
}

extern "C" __global__ __launch_bounds__(512, 2)
void lstm_fused(const float* __restrict__ xin,
  const float* w0i, const float* w0h, const float* b0i, const float* b0h,
  const float* w1i, const float* w1h, const float* b1i, const float* b1h,
  const float* w2i, const float* w2h, const float* b2i, const float* b2h,
  const float* w3i, const float* w3h, const float* b3i, const float* b3h,
  const float* __restrict__ lw, const float* __restrict__ lb,
  float* __restrict__ out, f16_t* plane)
{
  __shared__ __align__(16) f16_t hbuf0[BT*128];  // 4 KB (double-buffered h)
  __shared__ __align__(16) f16_t hbuf1[BT*128];  // 4 KB
  __shared__ float h_fin[BT*64];                 // 4 KB

  const int b0 = (int)blockIdx.x * BT;

  // L0: 8 -> 128, fp32 input, writes fp16 plane
  run_layer<8,   128, 0, true,  false>(w0i,w0h,b0i,b0h, xin, nullptr, plane,
                                       b0, hbuf0, hbuf1, h_fin);
  asm volatile("s_waitcnt vmcnt(0) lgkmcnt(0)" ::: "memory");
  __syncthreads();
  // L1: 128 -> 128, in-place on plane (slot t+2 read 2 barriers before overwrite)
  run_layer<128, 128, 1, true,  false>(w1i,w1h,b1i,b1h, nullptr, plane, plane,
                                       b0, hbuf0, hbuf1, h_fin);
  asm volatile("s_waitcnt vmcnt(0) lgkmcnt(0)" ::: "memory");
  __syncthreads();
  // L2: 128 -> 64, writes first 64 cols of each slot in-place
  run_layer<128, 64,  1, true,  false>(w2i,w2h,b2i,b2h, nullptr, plane, plane,
                                       b0, hbuf0, hbuf1, h_fin);
  asm volatile("s_waitcnt vmcnt(0) lgkmcnt(0)" ::: "memory");
  __syncthreads();
  // L3: 64 -> 64, no sequence output; final h kept fp32 in LDS
  run_layer<64,  64,  1, false, true >(w3i,w3h,b3i,b3h, nullptr, plane, nullptr,
                                       b0, hbuf0, hbuf1, h_fin);
  __syncthreads();

  // final linear: out[b] = h_fin[b,:] . lw + lb  (wave handles 2 rows)
  const int wv = (int)threadIdx.x >> 6;
  const int ln = (int)threadIdx.x & 63;
  #pragma unroll
  for (int rr = 0; rr < 2; ++rr) {
    const int row = wv*2 + rr;
    float v = h_fin[row*64 + ln] * lw[ln];
    #pragma unroll
    for (int m = 32; m >= 1; m >>= 1) v += __shfl_xor(v, m, 64);
    if (ln == 0) out[b0 + row] = v + lb[0];
  }
}

extern "C" void kernel_launch(void* const* d_in, const int* in_sizes, int n_in,
                              void* d_out, int out_size, void* d_ws, size_t ws_size,
                              hipStream_t stream) {
  const float* xin = (const float*)d_in[0];
  const float* w0i = (const float*)d_in[1];
  const float* w0h = (const float*)d_in[2];
  const float* b0i = (const float*)d_in[3];
  const float* b0h = (const float*)d_in[4];
  const float* w1i = (const float*)d_in[5];
  const float* w1h = (const float*)d_in[6];
  const float* b1i = (const float*)d_in[7];
  const float* b1h = (const float*)d_in[8];
  const float* w2i = (const float*)d_in[9];
  const float* w2h = (const float*)d_in[10];
  const float* b2i = (const float*)d_in[11];
  const float* b2h = (const float*)d_in[12];
  const float* w3i = (const float*)d_in[13];
  const float* w3h = (const float*)d_in[14];
  const float* b3i = (const float*)d_in[15];
  const float* b3h = (const float*)d_in[16];
  const float* lw  = (const float*)d_in[17];
  const float* lb  = (const float*)d_in[18];
  float* out = (float*)d_out;
  f16_t* plane = (f16_t*)d_ws;   // 1024*512*128 fp16 = 134 MB

  lstm_fused<<<64, 512, 0, stream>>>(xin,
      w0i,w0h,b0i,b0h, w1i,w1h,b1i,b1h, w2i,w2h,b2i,b2h, w3i,w3h,b3i,b3h,
      lw, lb, out, plane);
}

// Round 4
// 1199.476 us; speedup vs baseline: 13.0954x; 1.4570x over previous
//
#include <hip/hip_runtime.h>

#define DEVINL __device__ __forceinline__

typedef _Float16 f16_t;
typedef _Float16 f16x8 __attribute__((ext_vector_type(8)));
typedef float    f32x4 __attribute__((ext_vector_type(4)));

static constexpr int SEQ  = 512;   // sequence length
static constexpr int BT   = 16;    // batch rows per block (= MFMA M)
static constexpr int NW   = 8;     // waves per block
static constexpr int RING = 128;   // ring capacity (steps); 84MB total streams

// f16-element offsets of the three layer-boundary streams in d_ws
static constexpr size_t S0_OFF = 0;                          // L0->L1: 64*128*2048
static constexpr size_t S1_OFF = (size_t)64 * RING * 2048;   // L1->L2
static constexpr size_t S2_OFF = S1_OFF * 2;                 // L2->L3: 64*128*1024
static constexpr size_t FLAG_OFF_B = 88080384;               // 84 MiB, byte offset of flags

DEVINL f32x4 mfma16(f16x8 a, f16x8 b, f32x4 c) {
  return __builtin_amdgcn_mfma_f32_16x16x32_f16(a, b, c, 0, 0, 0);
}
DEVINL float fast_sigmoid(float x) {
  float e = __builtin_amdgcn_exp2f(-1.442695040888963f * x);
  return __builtin_amdgcn_rcpf(1.0f + e);
}
DEVINL float fast_tanh(float x) {
  x = fminf(40.0f, fmaxf(-40.0f, x));
  float e = __builtin_amdgcn_exp2f(-2.885390081777927f * x); // exp(-2x)
  return (1.0f - e) * __builtin_amdgcn_rcpf(1.0f + e);
}
// LDS-only barrier: don't drain vmcnt (stream loads/stores stay in flight)
DEVINL void sync_raw() {
  asm volatile("s_waitcnt lgkmcnt(0)" ::: "memory");
  __builtin_amdgcn_s_barrier();
  asm volatile("" ::: "memory");
}

// ---- cross-XCD stream primitives (agent scope -> coherent at MALL/L3) ----
DEVINL int  ld_flag(const int* p) { return __hip_atomic_load(p, __ATOMIC_RELAXED, __HIP_MEMORY_SCOPE_AGENT); }
DEVINL void st_flag(int* p, int v) { __hip_atomic_store(p, v, __ATOMIC_RELAXED, __HIP_MEMORY_SCOPE_AGENT); }
DEVINL void wait_ge(const int* p, int tgt) {
  while (ld_flag(p) < tgt) __builtin_amdgcn_s_sleep(4);
}
DEVINL void st_h16(f16_t* p, f16_t v) {
  __hip_atomic_store((unsigned short*)p, __builtin_bit_cast(unsigned short, v),
                     __ATOMIC_RELAXED, __HIP_MEMORY_SCOPE_AGENT);
}
struct u64x2 { unsigned long long x, y; };
DEVINL f16x8 ld_h16x8(const f16_t* p) {
  u64x2 t;
  t.x = __hip_atomic_load((const unsigned long long*)p,       __ATOMIC_RELAXED, __HIP_MEMORY_SCOPE_AGENT);
  t.y = __hip_atomic_load(((const unsigned long long*)p) + 1, __ATOMIC_RELAXED, __HIP_MEMORY_SCOPE_AGENT);
  return __builtin_bit_cast(f16x8, t);
}

// One pipeline stage: layer l for one 16-row batch tile, all 512 steps.
// XMODE 0: x = fp32 input_seq. XMODE 1: x = f16 ring-stream slot (atomic agent loads).
// PROD: write h to output ring (atomic u16 stores) + publish prog every 4 steps
//       via s_waitcnt vmcnt(4) (this step's 4 stores stay outstanding -> no drain stall).
// CONS: gate on upstream prog (flag load prefetched one group ahead -> ~0 poll stall),
//       publish consumer progress every 32 steps for ring back-pressure.
template<int LIN, int H, int XMODE, bool PROD, bool CONS, bool LAST>
DEVINL void run_layer(const float* __restrict__ wih, const float* __restrict__ whh,
                      const float* __restrict__ bih, const float* __restrict__ bhh,
                      const float* __restrict__ x0,
                      const f16_t* __restrict__ sin_, f16_t* __restrict__ sout_,
                      const int* prog_up, int* cons_self,
                      int* prog_self, const int* cons_down,
                      int b0, f16_t* hbA, f16_t* hbB, float* h_fin)
{
  constexpr int H16 = H/16;
  constexpr int KX  = (XMODE==0) ? 1 : LIN/32;
  constexpr int KH  = H/32;
  constexpr int SLI = 16*LIN;                  // input slot elems (XMODE1)
  constexpr int SLO = 16*H;                    // output slot elems

  const int tid = (int)threadIdx.x;
  const int wv = tid >> 6, ln = tid & 63, lr = ln & 15, lg = ln >> 4;
  const bool act = (wv < H16);
  const int j = wv*16 + lr;                    // this lane's hidden col

  // ---- weight B-fragments: wf[gate][kt], lane holds col n=g*H+j, k=kt*32+lg*8+i ----
  f16x8 wf[4][KX+KH];
  float bias4[4];
  if (act) {
    #pragma unroll
    for (int g = 0; g < 4; ++g) {
      const int n = g*H + j;
      bias4[g] = bih[n] + bhh[n];
      #pragma unroll
      for (int kt = 0; kt < KX; ++kt)
        #pragma unroll
        for (int i = 0; i < 8; ++i) {
          const int k = kt*32 + lg*8 + i;
          wf[g][kt][i] = (f16_t)((k < LIN) ? wih[n*LIN + k] : 0.0f);  // L0 pads 8->32
        }
      #pragma unroll
      for (int kt = 0; kt < KH; ++kt)
        #pragma unroll
        for (int i = 0; i < 8; ++i)
          wf[g][KX+kt][i] = (f16_t)whh[n*H + kt*32 + lg*8 + i];
    }
  }

  for (int z = tid; z < BT*H; z += NW*64) { hbA[z] = (f16_t)0.0f; hbB[z] = (f16_t)0.0f; }
  float c4[4] = {0.0f, 0.0f, 0.0f, 0.0f};

  auto loadx = [&](int t, f16x8 (&xr)[KX]) {
    if constexpr (XMODE == 0) {
      if (lg == 0) {
        const float* p = x0 + ((size_t)(b0+lr)*SEQ + t)*8;
        #pragma unroll
        for (int i = 0; i < 8; ++i) xr[0][i] = (f16_t)p[i];
      } else {
        #pragma unroll
        for (int i = 0; i < 8; ++i) xr[0][i] = (f16_t)0.0f;
      }
    } else {
      const f16_t* base = sin_ + (size_t)(t & (RING-1))*SLI + lr*LIN + lg*8;
      #pragma unroll
      for (int kt = 0; kt < KX; ++kt) xr[kt] = ld_h16x8(base + kt*32);
    }
  };

  // ---- gate on upstream before touching slot 0/1; prefetch flag for group 1 ----
  int fl_up = 0;
  if constexpr (CONS) { wait_ge(prog_up, 6); fl_up = ld_flag(prog_up); }

  // ---- prologue: accA = bias + x_0 path; xA = x_1 ----
  f32x4 accA[4], accB[4];
  f16x8 xA[KX], xB[KX];
  if (act) {
    f16x8 xr0[KX];
    loadx(0, xr0);
    #pragma unroll
    for (int g = 0; g < 4; ++g) {
      f32x4 a = {bias4[g], bias4[g], bias4[g], bias4[g]};
      accA[g] = a;
    }
    #pragma unroll
    for (int kt = 0; kt < KX; ++kt)
      #pragma unroll
      for (int g = 0; g < 4; ++g) accA[g] = mfma16(xr0[kt], wf[g][kt], accA[g]);
    loadx(1, xA);
  }
  __syncthreads();

  auto step = [&](int t, bool pub, f32x4 (&ac)[4], f32x4 (&an)[4],
                  f16x8 (&xc)[KX], f16x8 (&xn)[KX], f16_t* hr, f16_t* hw) {
    if (act) {
      // h-path MFMAs: h_{t-1} from swizzled LDS (conflict-free b128)
      #pragma unroll
      for (int kt = 0; kt < KH; ++kt) {
        const int chunk = ((kt*4 + lg) ^ (lr & 7)) * 8;
        const f16x8 ah = *(const f16x8*)&hr[lr*H + chunk];
        #pragma unroll
        for (int g = 0; g < 4; ++g) ac[g] = mfma16(ah, wf[g][KX+kt], ac[g]);
      }
      // prefetch x_{t+2}
      const int tf = (t+2 < SEQ) ? t+2 : SEQ-1;
      loadx(tf, xn);
      // next-step acc: bias + x_{t+1} path (independent of h_t)
      #pragma unroll
      for (int g = 0; g < 4; ++g) {
        f32x4 a = {bias4[g], bias4[g], bias4[g], bias4[g]};
        an[g] = a;
      }
      #pragma unroll
      for (int kt = 0; kt < KX; ++kt)
        #pragma unroll
        for (int g = 0; g < 4; ++g) an[g] = mfma16(xc[kt], wf[g][kt], an[g]);

      // gates in registers; h -> LDS (recurrence) + stream (next layer)
      f16_t* ob = nullptr;
      if constexpr (PROD) ob = sout_ + (size_t)(t & (RING-1))*SLO;
      #pragma unroll
      for (int r = 0; r < 4; ++r) {
        const int b = lg*4 + r;
        const float iv = fast_sigmoid(ac[0][r]);
        const float fv = fast_sigmoid(ac[1][r]);
        const float gv = fast_tanh(ac[2][r]);
        const float ov = fast_sigmoid(ac[3][r]);
        c4[r] = fv*c4[r] + iv*gv;
        const float h = ov * fast_tanh(c4[r]);
        const f16_t hh = (f16_t)h;
        hw[b*H + (j ^ ((b & 7) << 3))] = hh;
        if constexpr (PROD) st_h16(ob + b*H + j, hh);
        if constexpr (LAST) if (t == SEQ-1) h_fin[b*64 + j] = h;
      }
    }
    if (pub) {
      // leave only this step's <=4 stream stores outstanding; everything older
      // has retired (vmcnt counts in order) -> safe to publish prog = t.
      asm volatile("s_waitcnt vmcnt(4) lgkmcnt(0)" ::: "memory");
      __builtin_amdgcn_s_barrier();
      asm volatile("" ::: "memory");
      if (tid == 0) {
        if constexpr (PROD) st_flag(prog_self, t);
        if constexpr (CONS) if (((t+1) & 31) == 0) st_flag(cons_self, t-3);
      }
    } else {
      sync_raw();
    }
  };

  for (int t0 = 0; t0 < SEQ; t0 += 4) {
    if (t0 > 0) {
      if constexpr (CONS) {
        const int tgt = (t0+6 < SEQ) ? t0+6 : SEQ;
        if (fl_up < tgt) wait_ge(prog_up, tgt);   // slow path only during fill
        fl_up = ld_flag(prog_up);                 // prefetch for next boundary
      }
      if constexpr (PROD)
        if (t0 >= RING-4) wait_ge(cons_down, t0 - (RING-8));  // ring back-pressure
    }
    step(t0,   false, accA, accB, xA, xB, hbB, hbA);
    step(t0+1, false, accB, accA, xB, xA, hbA, hbB);
    step(t0+2, false, accA, accB, xA, xB, hbB, hbA);
    step(t0+3, true,  accB, accA, xB, xA, hbA, hbB);
  }

  // final: full drain, publish completion
  asm volatile("s_waitcnt vmcnt(0) lgkmcnt(0)" ::: "memory");
  __builtin_amdgcn_s_barrier();
  asm volatile("" ::: "memory");
  if (tid == 0) {
    if constexpr (PROD) st_flag(prog_self, SEQ);
    if constexpr (CONS) st_flag(cons_self, SEQ);
  }
}

extern "C" __global__ void lstm_init_flags(int* f) {
  const int i = (int)blockIdx.x * (int)blockDim.x + (int)threadIdx.x;
  if (i < 6144) f[i] = 0;
}

// 256 blocks: block (bid&3)=layer, (bid>>2)=batch tile. Capacity >= 1 block/CU
// (12KB LDS, <=256 VGPR at __launch_bounds__(512,2)) -> all 256 resident; the
// consumer<-producer dependency can always make progress (no deadlock).
extern "C" __global__ __launch_bounds__(512, 2)
void lstm_pipe(const float* __restrict__ xin,
  const float* w0i, const float* w0h, const float* b0i, const float* b0h,
  const float* w1i, const float* w1h, const float* b1i, const float* b1h,
  const float* w2i, const float* w2h, const float* b2i, const float* b2h,
  const float* w3i, const float* w3h, const float* b3i, const float* b3h,
  const float* __restrict__ lw, const float* __restrict__ lb,
  float* __restrict__ out, f16_t* ws16, int* flags)
{
  __shared__ __align__(16) f16_t hbuf0[BT*128];
  __shared__ __align__(16) f16_t hbuf1[BT*128];
  __shared__ float h_fin[BT*64];

  const int bid = (int)blockIdx.x;
  const int l = bid & 3, bt = bid >> 2, b0 = bt * BT;
  int* progf = flags;
  int* consf = flags + 3*64*16;
  int* P0 = progf + (0*64+bt)*16; int* C0 = consf + (0*64+bt)*16;
  int* P1 = progf + (1*64+bt)*16; int* C1 = consf + (1*64+bt)*16;
  int* P2 = progf + (2*64+bt)*16; int* C2 = consf + (2*64+bt)*16;

  f16_t* s0 = ws16 + S0_OFF + (size_t)bt * RING * 2048;
  f16_t* s1 = ws16 + S1_OFF + (size_t)bt * RING * 2048;
  f16_t* s2 = ws16 + S2_OFF + (size_t)bt * RING * 1024;

  if (l == 0) {
    run_layer<8,   128, 0, true,  false, false>(w0i,w0h,b0i,b0h, xin, nullptr, s0,
        nullptr, nullptr, P0, C0, b0, hbuf0, hbuf1, h_fin);
  } else if (l == 1) {
    run_layer<128, 128, 1, true,  true,  false>(w1i,w1h,b1i,b1h, nullptr, s0, s1,
        P0, C0, P1, C1, b0, hbuf0, hbuf1, h_fin);
  } else if (l == 2) {
    run_layer<128, 64,  1, true,  true,  false>(w2i,w2h,b2i,b2h, nullptr, s1, s2,
        P1, C1, P2, C2, b0, hbuf0, hbuf1, h_fin);
  } else {
    run_layer<64,  64,  1, false, true,  true >(w3i,w3h,b3i,b3h, nullptr, s2, nullptr,
        P2, C2, nullptr, nullptr, b0, hbuf0, hbuf1, h_fin);
    // final linear: out[b] = h_fin[b,:] . lw + lb
    const int wv = (int)threadIdx.x >> 6;
    const int ln = (int)threadIdx.x & 63;
    #pragma unroll
    for (int rr = 0; rr < 2; ++rr) {
      const int row = wv*2 + rr;
      float v = h_fin[row*64 + ln] * lw[ln];
      #pragma unroll
      for (int m = 32; m >= 1; m >>= 1) v += __shfl_xor(v, m, 64);
      if (ln == 0) out[b0 + row] = v + lb[0];
    }
  }
}

extern "C" void kernel_launch(void* const* d_in, const int* in_sizes, int n_in,
                              void* d_out, int out_size, void* d_ws, size_t ws_size,
                              hipStream_t stream) {
  const float* xin = (const float*)d_in[0];
  const float* w0i = (const float*)d_in[1];
  const float* w0h = (const float*)d_in[2];
  const float* b0i = (const float*)d_in[3];
  const float* b0h = (const float*)d_in[4];
  const float* w1i = (const float*)d_in[5];
  const float* w1h = (const float*)d_in[6];
  const float* b1i = (const float*)d_in[7];
  const float* b1h = (const float*)d_in[8];
  const float* w2i = (const float*)d_in[9];
  const float* w2h = (const float*)d_in[10];
  const float* b2i = (const float*)d_in[11];
  const float* b2h = (const float*)d_in[12];
  const float* w3i = (const float*)d_in[13];
  const float* w3h = (const float*)d_in[14];
  const float* b3i = (const float*)d_in[15];
  const float* b3h = (const float*)d_in[16];
  const float* lw  = (const float*)d_in[17];
  const float* lb  = (const float*)d_in[18];
  float* out = (float*)d_out;

  f16_t* ws16 = (f16_t*)d_ws;                       // ~84 MB streams
  int* flags  = (int*)((char*)d_ws + FLAG_OFF_B);   // 24 KB flags

  lstm_init_flags<<<12, 512, 0, stream>>>(flags);   // re-zero per launch (replay-safe)
  lstm_pipe<<<256, 512, 0, stream>>>(xin,
      w0i,w0h,b0i,b0h, w1i,w1h,b1i,b1h, w2i,w2h,b2i,b2h, w3i,w3h,b3i,b3h,
      lw, lb, out, ws16, flags);
}

// Round 6
// 1144.482 us; speedup vs baseline: 13.7247x; 1.0481x over previous
//
#include <hip/hip_runtime.h>

#define DEVINL __device__ __forceinline__

typedef _Float16 f16_t;
typedef _Float16 f16x8 __attribute__((ext_vector_type(8)));
typedef float    f32x4 __attribute__((ext_vector_type(4)));
typedef unsigned long long u64;

static constexpr int SEQ  = 512;   // sequence length
static constexpr int BT   = 16;    // batch rows per block (= MFMA M)
static constexpr int NW   = 8;     // waves per block
static constexpr int RING = 128;   // ring capacity (steps)

// f16-element offsets of the three layer-boundary streams in d_ws
static constexpr size_t S0_OFF = 0;                          // L0->L1: 64*128*2048
static constexpr size_t S1_OFF = (size_t)64 * RING * 2048;   // L1->L2
static constexpr size_t S2_OFF = S1_OFF * 2;                 // L2->L3: 64*128*1024
static constexpr size_t FLAG_OFF_B = 88080384;               // byte offset of flags

DEVINL f32x4 mfma16(f16x8 a, f16x8 b, f32x4 c) {
  return __builtin_amdgcn_mfma_f32_16x16x32_f16(a, b, c, 0, 0, 0);
}

// LDS-only barrier: don't drain vmcnt (stream loads/stores stay in flight)
DEVINL void sync_raw() {
  asm volatile("s_waitcnt lgkmcnt(0)" ::: "memory");
  __builtin_amdgcn_s_barrier();
  asm volatile("" ::: "memory");
}
DEVINL void sync_full() {
  asm volatile("s_waitcnt vmcnt(0) lgkmcnt(0)" ::: "memory");
  __builtin_amdgcn_s_barrier();
  asm volatile("" ::: "memory");
}

// ---- cross-XCD stream primitives (agent scope, all dword-multiple: no CAS) ----
DEVINL int  ld_flag(const int* p) { return __hip_atomic_load(p, __ATOMIC_RELAXED, __HIP_MEMORY_SCOPE_AGENT); }
DEVINL void st_flag(int* p, int v) { __hip_atomic_store(p, v, __ATOMIC_RELAXED, __HIP_MEMORY_SCOPE_AGENT); }
DEVINL void wait_ge(const int* p, int tgt) {
  while (ld_flag(p) < tgt) __builtin_amdgcn_s_sleep(2);
}
DEVINL void st_u64(u64* p, u64 v) { __hip_atomic_store(p, v, __ATOMIC_RELAXED, __HIP_MEMORY_SCOPE_AGENT); }
struct u64x2 { u64 x, y; };
DEVINL f16x8 ld_h16x8(const f16_t* p) {
  u64x2 t;
  t.x = __hip_atomic_load((const u64*)p,       __ATOMIC_RELAXED, __HIP_MEMORY_SCOPE_AGENT);
  t.y = __hip_atomic_load(((const u64*)p) + 1, __ATOMIC_RELAXED, __HIP_MEMORY_SCOPE_AGENT);
  return __builtin_bit_cast(f16x8, t);
}

// One pipeline stage: layer l for one 16-row batch tile, all 512 steps.
// XMODE 0: x = fp32 input_seq. XMODE 1: x = f16 ring slot in the producer's
//   SWIZZLED layout: element (b, col) at slot[b*LIN + (col ^ ((b&7)<<3))];
//   the A-fragment read folds the XOR into the chunk index.
// PROD: per step t>=1, copy h(t-1) LDS->stream as one u64/lane (raw swizzled
//   copy, coalesced); EPILOGUE copies h(SEQ-1) (R5 bug: it was never streamed,
//   consumer's last step read stale slot data -> exactly the output timestep).
//   Publish P = t0-2 every 4 steps after a vmcnt(0) sync.
// CONS: gate on prog_up with one-group-prefetched flag; publish consumer
//   progress every 32 steps for ring back-pressure.
template<int LIN, int H, int XMODE, bool PROD, bool CONS, bool LAST>
DEVINL void run_layer(const float* __restrict__ wih, const float* __restrict__ whh,
                      const float* __restrict__ bih, const float* __restrict__ bhh,
                      const float* __restrict__ x0,
                      const f16_t* __restrict__ sin_, f16_t* __restrict__ sout_,
                      const int* prog_up, int* cons_self,
                      int* prog_self, const int* cons_down,
                      int b0, f16_t* hbA, f16_t* hbB, float* h_fin)
{
  constexpr int H16 = H/16;
  constexpr int KX  = (XMODE==0) ? 1 : LIN/32;
  constexpr int KH  = H/32;
  constexpr int SLI = 16*LIN;                  // input slot elems (XMODE1)
  constexpr int SLO = 16*H;                    // output slot elems

  const int tid = (int)threadIdx.x;
  const int wv = tid >> 6, ln = tid & 63, lr = ln & 15, lg = ln >> 4;
  const bool act = (wv < H16);
  const int j = wv*16 + lr;                    // this lane's hidden col

  // ---- weight B-fragments: wf[gate][kt], lane holds col n=g*H+j, k=kt*32+lg*8+i ----
  f16x8 wf[4][KX+KH];
  float bias4[4];
  if (act) {
    #pragma unroll
    for (int g = 0; g < 4; ++g) {
      const int n = g*H + j;
      bias4[g] = bih[n] + bhh[n];
      #pragma unroll
      for (int kt = 0; kt < KX; ++kt)
        #pragma unroll
        for (int i = 0; i < 8; ++i) {
          const int k = kt*32 + lg*8 + i;
          wf[g][kt][i] = (f16_t)((k < LIN) ? wih[n*LIN + k] : 0.0f);  // L0 pads 8->32
        }
      #pragma unroll
      for (int kt = 0; kt < KH; ++kt)
        #pragma unroll
        for (int i = 0; i < 8; ++i)
          wf[g][KX+kt][i] = (f16_t)whh[n*H + kt*32 + lg*8 + i];
    }
  }

  for (int z = tid; z < BT*H; z += NW*64) { hbA[z] = (f16_t)0.0f; hbB[z] = (f16_t)0.0f; }
  float c4[4] = {0.0f, 0.0f, 0.0f, 0.0f};

  auto loadx = [&](int t, f16x8 (&xr)[KX]) {
    if constexpr (XMODE == 0) {
      if (lg == 0) {
        const float* p = x0 + ((size_t)(b0+lr)*SEQ + t)*8;
        #pragma unroll
        for (int i = 0; i < 8; ++i) xr[0][i] = (f16_t)p[i];
      } else {
        #pragma unroll
        for (int i = 0; i < 8; ++i) xr[0][i] = (f16_t)0.0f;
      }
    } else {
      const f16_t* base = sin_ + (size_t)(t & (RING-1))*SLI + lr*LIN;
      #pragma unroll
      for (int kt = 0; kt < KX; ++kt) {
        const int chunk = ((kt*4 + lg) ^ (lr & 7)) * 8;   // swizzle folded in
        xr[kt] = ld_h16x8(base + chunk);
      }
    }
  };

  // ---- initial consumer gate (covers prologue + first group reads <= x(5)) ----
  int fl_up = 0, fl_dn = 0;
  if constexpr (CONS) { wait_ge(prog_up, 5); fl_up = ld_flag(prog_up); }

  // ---- prologue: accA = bias + x_0 path; xA = x_1 ----
  f32x4 accA[4], accB[4];
  f16x8 xA[KX], xB[KX];
  if (act) {
    f16x8 xr0[KX];
    loadx(0, xr0);
    #pragma unroll
    for (int g = 0; g < 4; ++g) {
      f32x4 a = {bias4[g], bias4[g], bias4[g], bias4[g]};
      accA[g] = a;
    }
    #pragma unroll
    for (int kt = 0; kt < KX; ++kt)
      #pragma unroll
      for (int g = 0; g < 4; ++g) accA[g] = mfma16(xr0[kt], wf[g][kt], accA[g]);
    loadx(1, xA);
  }
  __syncthreads();

  constexpr float K1 = 1.442695040888963f;   // log2(e)
  constexpr float K2 = 2.885390081777927f;   // 2*log2(e)

  auto step = [&](int t, bool full, f32x4 (&ac)[4], f32x4 (&an)[4],
                  f16x8 (&xc)[KX], f16x8 (&xn)[KX], f16_t* hr, f16_t* hw) {
    if (act) {
      // stream-copy h(t-1) (raw swizzled): 1 ds_read_b64 + 1 u64 agent store
      if constexpr (PROD) {
        if (t >= 1) {
          const u64 v = *(const u64*)(hr + (size_t)tid*4);
          u64* ob = (u64*)(sout_ + (size_t)((t-1) & (RING-1))*SLO);
          st_u64(ob + tid, v);
        }
      }
      // prefetch x_{t+2}
      const int tf = (t+2 < SEQ) ? t+2 : SEQ-1;
      loadx(tf, xn);
      // h-path MFMAs: h_{t-1} from swizzled LDS (conflict-free b128)
      #pragma unroll
      for (int kt = 0; kt < KH; ++kt) {
        const int chunk = ((kt*4 + lg) ^ (lr & 7)) * 8;
        const f16x8 ah = *(const f16x8*)&hr[lr*H + chunk];
        #pragma unroll
        for (int g = 0; g < 4; ++g) ac[g] = mfma16(ah, wf[g][KX+kt], ac[g]);
      }
      // next-step acc: bias + x_{t+1} path (independent of h_t)
      #pragma unroll
      for (int g = 0; g < 4; ++g) {
        f32x4 a = {bias4[g], bias4[g], bias4[g], bias4[g]};
        an[g] = a;
      }
      #pragma unroll
      for (int kt = 0; kt < KX; ++kt)
        #pragma unroll
        for (int g = 0; g < 4; ++g) an[g] = mfma16(xc[kt], wf[g][kt], an[g]);

      // gates: 5 exp2 + 3 rcp per row (combined reciprocals)
      #pragma unroll
      for (int r = 0; r < 4; ++r) {
        const int b = lg*4 + r;
        const float pi_ = fminf(60.f, fmaxf(-60.f, ac[0][r]));
        const float pf_ = fminf(60.f, fmaxf(-60.f, ac[1][r]));
        const float pg_ = fminf(42.f, fmaxf(-42.f, ac[2][r]));
        const float po_ = fminf(60.f, fmaxf(-60.f, ac[3][r]));
        const float ei = __builtin_amdgcn_exp2f(-K1*pi_);
        const float ef = __builtin_amdgcn_exp2f(-K1*pf_);
        const float eg = __builtin_amdgcn_exp2f(-K2*pg_);
        const float eo = __builtin_amdgcn_exp2f(-K1*po_);
        const float fv = __builtin_amdgcn_rcpf(1.f + ef);
        const float ig = (1.f - eg) * __builtin_amdgcn_rcpf((1.f + ei)*(1.f + eg));
        const float cv = fv*c4[r] + ig;
        c4[r] = cv;
        const float cc = fminf(42.f, fmaxf(-42.f, cv));
        const float ec = __builtin_amdgcn_exp2f(-K2*cc);
        const float h  = (1.f - ec) * __builtin_amdgcn_rcpf((1.f + eo)*(1.f + ec));
        hw[b*H + (j ^ ((b & 7) << 3))] = (f16_t)h;
        if constexpr (LAST) if (t == SEQ-1) h_fin[b*64 + j] = h;
      }
    }
    if (full) sync_full(); else sync_raw();
  };

  for (int t0 = 0; t0 < SEQ; t0 += 4) {
    if (t0 > 0) {
      // previous group ended with sync_full (PROD) -> all copies <= t0-2 visible
      if constexpr (PROD) if (tid == 0) st_flag(prog_self, t0 - 2);
      if constexpr (CONS) {
        if ((t0 & 31) == 0 && tid == 0) st_flag(cons_self, t0 - 1);
        const int tgt = (t0+5 < SEQ-1) ? t0+5 : SEQ-1;
        if (fl_up < tgt) wait_ge(prog_up, tgt);
        fl_up = ld_flag(prog_up);                 // prefetch for next boundary
      }
      if constexpr (PROD) {
        if (t0 >= 124) {                          // ring back-pressure
          const int tgt = t0 - 124;
          if (fl_dn < tgt) wait_ge(cons_down, tgt);
          fl_dn = ld_flag(cons_down);
        }
      }
    }
    step(t0,   false, accA, accB, xA, xB, hbB, hbA);
    step(t0+1, false, accB, accA, xB, xA, hbA, hbB);
    step(t0+2, false, accA, accB, xA, xB, hbB, hbA);
    step(t0+3, PROD,  accB, accA, xB, xA, hbA, hbB);
  }

  // EPILOGUE (the R5 fix): stream h(SEQ-1), which the loop's shifted copy
  // never emitted. Last step (t=511, odd) wrote h into hbB.
  if constexpr (PROD) {
    if (act) {
      const u64 v = *(const u64*)(hbB + (size_t)tid*4);
      u64* ob = (u64*)(sout_ + (size_t)((SEQ-1) & (RING-1))*SLO);
      st_u64(ob + tid, v);
    }
  }
  sync_full();
  if (tid == 0) {
    if constexpr (PROD) st_flag(prog_self, SEQ);
    if constexpr (CONS) st_flag(cons_self, SEQ);
  }
}

extern "C" __global__ void lstm_init_flags(int* f) {
  const int i = (int)blockIdx.x * (int)blockDim.x + (int)threadIdx.x;
  if (i < 6144) f[i] = 0;
}

// 256 blocks: (bid&3)=layer, (bid>>2)=batch tile. One block/CU (register
// footprint forbids 2) -> all 256 resident -> pipeline always progresses.
extern "C" __global__ __launch_bounds__(512, 2)
void lstm_pipe(const float* __restrict__ xin,
  const float* w0i, const float* w0h, const float* b0i, const float* b0h,
  const float* w1i, const float* w1h, const float* b1i, const float* b1h,
  const float* w2i, const float* w2h, const float* b2i, const float* b2h,
  const float* w3i, const float* w3h, const float* b3i, const float* b3h,
  const float* __restrict__ lw, const float* __restrict__ lb,
  float* __restrict__ out, f16_t* ws16, int* flags)
{
  __shared__ __align__(16) f16_t hbuf0[BT*128];
  __shared__ __align__(16) f16_t hbuf1[BT*128];
  __shared__ float h_fin[BT*64];

  const int bid = (int)blockIdx.x;
  const int l = bid & 3, bt = bid >> 2, b0 = bt * BT;
  int* progf = flags;
  int* consf = flags + 3*64*16;
  int* P0 = progf + (0*64+bt)*16; int* C0 = consf + (0*64+bt)*16;
  int* P1 = progf + (1*64+bt)*16; int* C1 = consf + (1*64+bt)*16;
  int* P2 = progf + (2*64+bt)*16; int* C2 = consf + (2*64+bt)*16;

  f16_t* s0 = ws16 + S0_OFF + (size_t)bt * RING * 2048;
  f16_t* s1 = ws16 + S1_OFF + (size_t)bt * RING * 2048;
  f16_t* s2 = ws16 + S2_OFF + (size_t)bt * RING * 1024;

  if (l == 0) {
    run_layer<8,   128, 0, true,  false, false>(w0i,w0h,b0i,b0h, xin, nullptr, s0,
        nullptr, nullptr, P0, C0, b0, hbuf0, hbuf1, h_fin);
  } else if (l == 1) {
    run_layer<128, 128, 1, true,  true,  false>(w1i,w1h,b1i,b1h, nullptr, s0, s1,
        P0, C0, P1, C1, b0, hbuf0, hbuf1, h_fin);
  } else if (l == 2) {
    run_layer<128, 64,  1, true,  true,  false>(w2i,w2h,b2i,b2h, nullptr, s1, s2,
        P1, C1, P2, C2, b0, hbuf0, hbuf1, h_fin);
  } else {
    run_layer<64,  64,  1, false, true,  true >(w3i,w3h,b3i,b3h, nullptr, s2, nullptr,
        P2, C2, nullptr, nullptr, b0, hbuf0, hbuf1, h_fin);
    // final linear: out[b] = h_fin[b,:] . lw + lb
    const int wv = (int)threadIdx.x >> 6;
    const int ln = (int)threadIdx.x & 63;
    #pragma unroll
    for (int rr = 0; rr < 2; ++rr) {
      const int row = wv*2 + rr;
      float v = h_fin[row*64 + ln] * lw[ln];
      #pragma unroll
      for (int m = 32; m >= 1; m >>= 1) v += __shfl_xor(v, m, 64);
      if (ln == 0) out[b0 + row] = v + lb[0];
    }
  }
}

extern "C" void kernel_launch(void* const* d_in, const int* in_sizes, int n_in,
                              void* d_out, int out_size, void* d_ws, size_t ws_size,
                              hipStream_t stream) {
  const float* xin = (const float*)d_in[0];
  const float* w0i = (const float*)d_in[1];
  const float* w0h = (const float*)d_in[2];
  const float* b0i = (const float*)d_in[3];
  const float* b0h = (const float*)d_in[4];
  const float* w1i = (const float*)d_in[5];
  const float* w1h = (const float*)d_in[6];
  const float* b1i = (const float*)d_in[7];
  const float* b1h = (const float*)d_in[8];
  const float* w2i = (const float*)d_in[9];
  const float* w2h = (const float*)d_in[10];
  const float* b2i = (const float*)d_in[11];
  const float* b2h = (const float*)d_in[12];
  const float* w3i = (const float*)d_in[13];
  const float* w3h = (const float*)d_in[14];
  const float* b3i = (const float*)d_in[15];
  const float* b3h = (const float*)d_in[16];
  const float* lw  = (const float*)d_in[17];
  const float* lb  = (const float*)d_in[18];
  float* out = (float*)d_out;

  f16_t* ws16 = (f16_t*)d_ws;                       // ~80 MB streams
  int* flags  = (int*)((char*)d_ws + FLAG_OFF_B);   // 24 KB flags

  lstm_init_flags<<<12, 512, 0, stream>>>(flags);   // re-zero per launch (replay-safe)
  lstm_pipe<<<256, 512, 0, stream>>>(xin,
      w0i,w0h,b0i,b0h, w1i,w1h,b1i,b1h, w2i,w2h,b2i,b2h, w3i,w3h,b3i,b3h,
      lw, lb, out, ws16, flags);
}

// Round 7
// 1136.154 us; speedup vs baseline: 13.8253x; 1.0073x over previous
//
#include <hip/hip_runtime.h>

#define DEVINL __device__ __forceinline__

typedef _Float16 f16_t;
typedef _Float16 f16x8 __attribute__((ext_vector_type(8)));
typedef float    f32x4 __attribute__((ext_vector_type(4)));
typedef unsigned long long u64;

static constexpr int SEQ  = 512;   // sequence length
static constexpr int BT   = 16;    // batch rows per block (= MFMA M)
static constexpr int NW   = 8;     // waves per block
static constexpr int RING = 128;   // ring capacity (steps)

// f16-element offsets of the three layer-boundary streams in d_ws
static constexpr size_t S0_OFF = 0;                          // L0->L1: 64*128*2048
static constexpr size_t S1_OFF = (size_t)64 * RING * 2048;   // L1->L2
static constexpr size_t S2_OFF = S1_OFF * 2;                 // L2->L3: 64*128*1024
static constexpr size_t FLAG_OFF_B = 88080384;               // byte offset of flags

DEVINL f32x4 mfma16(f16x8 a, f16x8 b, f32x4 c) {
  return __builtin_amdgcn_mfma_f32_16x16x32_f16(a, b, c, 0, 0, 0);
}

// LDS-only barrier: don't drain vmcnt (stream loads/stores stay in flight)
DEVINL void sync_raw() {
  asm volatile("s_waitcnt lgkmcnt(0)" ::: "memory");
  __builtin_amdgcn_s_barrier();
  asm volatile("" ::: "memory");
}
DEVINL void sync_full() {
  asm volatile("s_waitcnt vmcnt(0) lgkmcnt(0)" ::: "memory");
  __builtin_amdgcn_s_barrier();
  asm volatile("" ::: "memory");
}

// ---- flags (rare; HIP agent-scope atomics are fine here) ----
DEVINL int  ld_flag(const int* p) { return __hip_atomic_load(p, __ATOMIC_RELAXED, __HIP_MEMORY_SCOPE_AGENT); }
DEVINL void st_flag(int* p, int v) { __hip_atomic_store(p, v, __ATOMIC_RELAXED, __HIP_MEMORY_SCOPE_AGENT); }
DEVINL void wait_ge(const int* p, int tgt) {
  while (ld_flag(p) < tgt) __builtin_amdgcn_s_sleep(2);
}

// ---- hot-loop data path: plain (non-atomic) cache-bypassing asm ops.
// sc0 sc1 on gfx950 = bypass L1+L2, read/write at MALL -> cross-XCD coherent
// for data whose producer drained vmcnt before publishing the flag.
DEVINL void gl_load16_coh(const f16_t* p, f16x8& r) {
  asm volatile("global_load_dwordx4 %0, %1, off sc0 sc1"
               : "=&v"(r) : "v"(p) : "memory");
}
DEVINL void gl_load32_f32(const float* p, f32x4& a, f32x4& b) {  // cached (immutable input)
  asm volatile("global_load_dwordx4 %0, %2, off\n\t"
               "global_load_dwordx4 %1, %2, off offset:16"
               : "=&v"(a), "=&v"(b) : "v"(p) : "memory");
}
DEVINL void gl_store8_coh(void* p, u64 v) {
  asm volatile("global_store_dwordx2 %0, %1, off sc0 sc1"
               :: "v"(p), "v"(v) : "memory");
}

// One pipeline stage: layer l for one 16-row batch tile, all 512 steps.
// All in-loop VMEM is inline asm -> counted s_waitcnt vmcnt(N) is exact:
// at step t we issue NLOAD loads (+1 store for PROD,t>=1); waiting to
// vmcnt(<=ops-just-issued) retires everything older, i.e. last step's x
// prefetch. Extra compiler VMEM (flag loads at chunk boundaries) only makes
// the wait stricter -> always safe.
template<int LIN, int H, int XMODE, bool PROD, bool CONS, bool LAST>
DEVINL void run_layer(const float* __restrict__ wih, const float* __restrict__ whh,
                      const float* __restrict__ bih, const float* __restrict__ bhh,
                      const float* __restrict__ x0,
                      const f16_t* __restrict__ sin_, f16_t* __restrict__ sout_,
                      const int* prog_up, int* cons_self,
                      int* prog_self, const int* cons_down,
                      int b0, f16_t* hbA, f16_t* hbB, float* h_fin)
{
  constexpr int H16   = H/16;
  constexpr int KX    = (XMODE==0) ? 1 : LIN/32;
  constexpr int KH    = H/32;
  constexpr int SLI   = 16*LIN;               // input slot elems (XMODE1)
  constexpr int SLO   = 16*H;                 // output slot elems
  constexpr int NLOAD = (XMODE==0) ? 2 : KX;  // asm load ops per step

  const int tid = (int)threadIdx.x;
  const int wv = tid >> 6, ln = tid & 63, lr = ln & 15, lg = ln >> 4;
  const bool act = (wv < H16);
  const int j = wv*16 + lr;                    // this lane's hidden col

  // ---- weight B-fragments: wf[gate][kt], lane holds col n=g*H+j, k=kt*32+lg*8+i ----
  f16x8 wf[4][KX+KH];
  float bias4[4];
  if (act) {
    #pragma unroll
    for (int g = 0; g < 4; ++g) {
      const int n = g*H + j;
      bias4[g] = bih[n] + bhh[n];
      #pragma unroll
      for (int kt = 0; kt < KX; ++kt)
        #pragma unroll
        for (int i = 0; i < 8; ++i) {
          const int k = kt*32 + lg*8 + i;
          wf[g][kt][i] = (f16_t)((k < LIN) ? wih[n*LIN + k] : 0.0f);  // L0 pads 8->32
        }
      #pragma unroll
      for (int kt = 0; kt < KH; ++kt)
        #pragma unroll
        for (int i = 0; i < 8; ++i)
          wf[g][KX+kt][i] = (f16_t)whh[n*H + kt*32 + lg*8 + i];
    }
  }

  for (int z = tid; z < BT*H; z += NW*64) { hbA[z] = (f16_t)0.0f; hbB[z] = (f16_t)0.0f; }
  float c4[4] = {0.0f, 0.0f, 0.0f, 0.0f};

  // issue (don't wait) the x loads for step t
  auto issue_loads = [&](int t, f16x8 (&xr)[KX], f32x4 (&pr)[2]) {
    if constexpr (XMODE == 0) {
      const float* p = x0 + ((size_t)(b0+lr)*SEQ + t)*8;   // all lanes: valid addr
      gl_load32_f32(p, pr[0], pr[1]);
    } else {
      const f16_t* base = sin_ + (size_t)(t & (RING-1))*SLI + lr*LIN;
      #pragma unroll
      for (int kt = 0; kt < KX; ++kt) {
        const int chunk = ((kt*4 + lg) ^ (lr & 7)) * 8;    // swizzle folded in
        gl_load16_coh(base + chunk, xr[kt]);
      }
    }
  };

  // ---- initial consumer gate: large slack so steady-state jitter is ring-absorbed ----
  int fl_up = 0, fl_dn = 0;
  if constexpr (CONS) { wait_ge(prog_up, 33); fl_up = ld_flag(prog_up); }

  // ---- prologue: accA = bias + x_0 path; then issue loads for x_1 ----
  f32x4 accA[4], accB[4];
  f16x8 xA[KX], xB[KX];
  f32x4 pA[2], pB[2];
  if (act) {
    f16x8 x0f[KX]; f32x4 p0[2];
    issue_loads(0, x0f, p0);
    asm volatile("s_waitcnt vmcnt(0)" ::: "memory");
    __builtin_amdgcn_sched_barrier(0);
    #pragma unroll
    for (int g = 0; g < 4; ++g) {
      f32x4 a = {bias4[g], bias4[g], bias4[g], bias4[g]};
      accA[g] = a;
    }
    if constexpr (XMODE == 0) {
      f16x8 xf;
      #pragma unroll
      for (int i = 0; i < 8; ++i) {
        const float v = (lg == 0) ? ((i < 4) ? p0[0][i] : p0[1][i-4]) : 0.0f;
        xf[i] = (f16_t)v;
      }
      #pragma unroll
      for (int g = 0; g < 4; ++g) accA[g] = mfma16(xf, wf[g][0], accA[g]);
    } else {
      #pragma unroll
      for (int kt = 0; kt < KX; ++kt)
        #pragma unroll
        for (int g = 0; g < 4; ++g) accA[g] = mfma16(x0f[kt], wf[g][kt], accA[g]);
    }
    issue_loads(1, xA, pA);
  }
  __syncthreads();

  constexpr float K1 = 1.442695040888963f;   // log2(e)
  constexpr float K2 = 2.885390081777927f;   // 2*log2(e)

  auto step = [&](int t, bool full, f32x4 (&ac)[4], f32x4 (&an)[4],
                  f16x8 (&xc)[KX], f32x4 (&pc)[2],
                  f16x8 (&xn)[KX], f32x4 (&pn)[2],
                  f16_t* hr, f16_t* hw) {
    if (act) {
      // 1) issue x prefetch for t+2
      const int tf = (t+2 < SEQ) ? t+2 : SEQ-1;
      issue_loads(tf, xn, pn);
      // 2) stream-copy h(t-1) (raw swizzled): ds_read_b64 + coherent store
      if constexpr (PROD) {
        if (t >= 1) {
          const u64 v = *(const u64*)(hr + (size_t)tid*4);
          gl_store8_coh((u64*)(sout_ + (size_t)((t-1) & (RING-1))*SLO) + tid, v);
        }
      }
      // 3) h-path MFMAs (LDS only; free to run under load latency)
      #pragma unroll
      for (int kt = 0; kt < KH; ++kt) {
        const int chunk = ((kt*4 + lg) ^ (lr & 7)) * 8;
        const f16x8 ah = *(const f16x8*)&hr[lr*H + chunk];
        #pragma unroll
        for (int g = 0; g < 4; ++g) ac[g] = mfma16(ah, wf[g][KX+kt], ac[g]);
      }
      // 4) counted wait: retire everything older than this step's VMEM ops
      //    -> xc/pc (issued last step) are ready. sched_barrier pins consumers.
      if constexpr (PROD) {
        if (t >= 1) { asm volatile("s_waitcnt vmcnt(%0)" :: "i"(NLOAD+1) : "memory"); }
        else        { asm volatile("s_waitcnt vmcnt(%0)" :: "i"(NLOAD)   : "memory"); }
      } else {
        asm volatile("s_waitcnt vmcnt(%0)" :: "i"(NLOAD) : "memory");
      }
      __builtin_amdgcn_sched_barrier(0);
      // 5) next-step acc: bias + x_{t+1} path
      #pragma unroll
      for (int g = 0; g < 4; ++g) {
        f32x4 a = {bias4[g], bias4[g], bias4[g], bias4[g]};
        an[g] = a;
      }
      if constexpr (XMODE == 0) {
        f16x8 xf;
        #pragma unroll
        for (int i = 0; i < 8; ++i) {
          const float v = (lg == 0) ? ((i < 4) ? pc[0][i] : pc[1][i-4]) : 0.0f;
          xf[i] = (f16_t)v;
        }
        #pragma unroll
        for (int g = 0; g < 4; ++g) an[g] = mfma16(xf, wf[g][0], an[g]);
      } else {
        #pragma unroll
        for (int kt = 0; kt < KX; ++kt)
          #pragma unroll
          for (int g = 0; g < 4; ++g) an[g] = mfma16(xc[kt], wf[g][kt], an[g]);
      }
      // 6) gates: 5 exp2 + 3 rcp per row
      #pragma unroll
      for (int r = 0; r < 4; ++r) {
        const int b = lg*4 + r;
        const float pi_ = fminf(60.f, fmaxf(-60.f, ac[0][r]));
        const float pf_ = fminf(60.f, fmaxf(-60.f, ac[1][r]));
        const float pg_ = fminf(42.f, fmaxf(-42.f, ac[2][r]));
        const float po_ = fminf(60.f, fmaxf(-60.f, ac[3][r]));
        const float ei = __builtin_amdgcn_exp2f(-K1*pi_);
        const float ef = __builtin_amdgcn_exp2f(-K1*pf_);
        const float eg = __builtin_amdgcn_exp2f(-K2*pg_);
        const float eo = __builtin_amdgcn_exp2f(-K1*po_);
        const float fv = __builtin_amdgcn_rcpf(1.f + ef);
        const float ig = (1.f - eg) * __builtin_amdgcn_rcpf((1.f + ei)*(1.f + eg));
        const float cv = fv*c4[r] + ig;
        c4[r] = cv;
        const float cc = fminf(42.f, fmaxf(-42.f, cv));
        const float ec = __builtin_amdgcn_exp2f(-K2*cc);
        const float h  = (1.f - ec) * __builtin_amdgcn_rcpf((1.f + eo)*(1.f + ec));
        hw[b*H + (j ^ ((b & 7) << 3))] = (f16_t)h;
        if constexpr (LAST) if (t == SEQ-1) h_fin[b*64 + j] = h;
      }
    }
    if (full) sync_full(); else sync_raw();
  };

  // chunked loop: cadence 8 for publish/check; back-pressure threshold 112
  for (int t0 = 0; t0 < SEQ; t0 += 8) {
    if (t0 > 0) {
      // previous chunk ended with sync_full (PROD) -> copies <= t0-2 visible
      if constexpr (PROD) if (tid == 0) st_flag(prog_self, t0 - 2);
      if constexpr (CONS) {
        if ((t0 & 31) == 0 && tid == 0) st_flag(cons_self, t0 - 1);
        const int tgt = (t0+9 < SEQ-1) ? t0+9 : SEQ-1;
        if (fl_up < tgt) wait_ge(prog_up, tgt);
        fl_up = ld_flag(prog_up);                 // prefetch for next boundary
      }
      if constexpr (PROD) {
        if (t0 >= 112) {                          // ring slot-reuse safety
          const int tgt = t0 - 112;
          if (fl_dn < tgt) wait_ge(cons_down, tgt);
          fl_dn = ld_flag(cons_down);
        }
      }
    }
    step(t0,   false, accA, accB, xA, pA, xB, pB, hbB, hbA);
    step(t0+1, false, accB, accA, xB, pB, xA, pA, hbA, hbB);
    step(t0+2, false, accA, accB, xA, pA, xB, pB, hbB, hbA);
    step(t0+3, false, accB, accA, xB, pB, xA, pA, hbA, hbB);
    step(t0+4, false, accA, accB, xA, pA, xB, pB, hbB, hbA);
    step(t0+5, false, accB, accA, xB, pB, xA, pA, hbA, hbB);
    step(t0+6, false, accA, accB, xA, pA, xB, pB, hbB, hbA);
    step(t0+7, PROD,  accB, accA, xB, pB, xA, pA, hbA, hbB);
  }

  // EPILOGUE: stream h(SEQ-1) (loop's shifted copy never emits it). t=511 odd -> hbB.
  if constexpr (PROD) {
    if (act) {
      const u64 v = *(const u64*)(hbB + (size_t)tid*4);
      gl_store8_coh((u64*)(sout_ + (size_t)((SEQ-1) & (RING-1))*SLO) + tid, v);
    }
  }
  sync_full();
  if (tid == 0) {
    if constexpr (PROD) st_flag(prog_self, SEQ);
    if constexpr (CONS) st_flag(cons_self, SEQ);
  }
}

extern "C" __global__ void lstm_init_flags(int* f) {
  const int i = (int)blockIdx.x * (int)blockDim.x + (int)threadIdx.x;
  if (i < 6144) f[i] = 0;
}

// 256 blocks: (bid&3)=layer, (bid>>2)=batch tile. One block/CU -> all resident.
extern "C" __global__ __launch_bounds__(512, 2)
void lstm_pipe(const float* __restrict__ xin,
  const float* w0i, const float* w0h, const float* b0i, const float* b0h,
  const float* w1i, const float* w1h, const float* b1i, const float* b1h,
  const float* w2i, const float* w2h, const float* b2i, const float* b2h,
  const float* w3i, const float* w3h, const float* b3i, const float* b3h,
  const float* __restrict__ lw, const float* __restrict__ lb,
  float* __restrict__ out, f16_t* ws16, int* flags)
{
  __shared__ __align__(16) f16_t hbuf0[BT*128];
  __shared__ __align__(16) f16_t hbuf1[BT*128];
  __shared__ float h_fin[BT*64];

  const int bid = (int)blockIdx.x;
  const int l = bid & 3, bt = bid >> 2, b0 = bt * BT;
  int* progf = flags;
  int* consf = flags + 3*64*16;
  int* P0 = progf + (0*64+bt)*16; int* C0 = consf + (0*64+bt)*16;
  int* P1 = progf + (1*64+bt)*16; int* C1 = consf + (1*64+bt)*16;
  int* P2 = progf + (2*64+bt)*16; int* C2 = consf + (2*64+bt)*16;

  f16_t* s0 = ws16 + S0_OFF + (size_t)bt * RING * 2048;
  f16_t* s1 = ws16 + S1_OFF + (size_t)bt * RING * 2048;
  f16_t* s2 = ws16 + S2_OFF + (size_t)bt * RING * 1024;

  if (l == 0) {
    run_layer<8,   128, 0, true,  false, false>(w0i,w0h,b0i,b0h, xin, nullptr, s0,
        nullptr, nullptr, P0, C0, b0, hbuf0, hbuf1, h_fin);
  } else if (l == 1) {
    run_layer<128, 128, 1, true,  true,  false>(w1i,w1h,b1i,b1h, nullptr, s0, s1,
        P0, C0, P1, C1, b0, hbuf0, hbuf1, h_fin);
  } else if (l == 2) {
    run_layer<128, 64,  1, true,  true,  false>(w2i,w2h,b2i,b2h, nullptr, s1, s2,
        P1, C1, P2, C2, b0, hbuf0, hbuf1, h_fin);
  } else {
    run_layer<64,  64,  1, false, true,  true >(w3i,w3h,b3i,b3h, nullptr, s2, nullptr,
        P2, C2, nullptr, nullptr, b0, hbuf0, hbuf1, h_fin);
    // final linear: out[b] = h_fin[b,:] . lw + lb
    const int wv = (int)threadIdx.x >> 6;
    const int ln = (int)threadIdx.x & 63;
    #pragma unroll
    for (int rr = 0; rr < 2; ++rr) {
      const int row = wv*2 + rr;
      float v = h_fin[row*64 + ln] * lw[ln];
      #pragma unroll
      for (int m = 32; m >= 1; m >>= 1) v += __shfl_xor(v, m, 64);
      if (ln == 0) out[b0 + row] = v + lb[0];
    }
  }
}

extern "C" void kernel_launch(void* const* d_in, const int* in_sizes, int n_in,
                              void* d_out, int out_size, void* d_ws, size_t ws_size,
                              hipStream_t stream) {
  const float* xin = (const float*)d_in[0];
  const float* w0i = (const float*)d_in[1];
  const float* w0h = (const float*)d_in[2];
  const float* b0i = (const float*)d_in[3];
  const float* b0h = (const float*)d_in[4];
  const float* w1i = (const float*)d_in[5];
  const float* w1h = (const float*)d_in[6];
  const float* b1i = (const float*)d_in[7];
  const float* b1h = (const float*)d_in[8];
  const float* w2i = (const float*)d_in[9];
  const float* w2h = (const float*)d_in[10];
  const float* b2i = (const float*)d_in[11];
  const float* b2h = (const float*)d_in[12];
  const float* w3i = (const float*)d_in[13];
  const float* w3h = (const float*)d_in[14];
  const float* b3i = (const float*)d_in[15];
  const float* b3h = (const float*)d_in[16];
  const float* lw  = (const float*)d_in[17];
  const float* lb  = (const float*)d_in[18];
  float* out = (float*)d_out;

  f16_t* ws16 = (f16_t*)d_ws;                       // ~80 MB streams
  int* flags  = (int*)((char*)d_ws + FLAG_OFF_B);   // 24 KB flags

  lstm_init_flags<<<12, 512, 0, stream>>>(flags);   // re-zero per launch (replay-safe)
  lstm_pipe<<<256, 512, 0, stream>>>(xin,
      w0i,w0h,b0i,b0h, w1i,w1h,b1i,b1h, w2i,w2h,b2i,b2h, w3i,w3h,b3i,b3h,
      lw, lb, out, ws16, flags);
}

// Round 8
// 756.527 us; speedup vs baseline: 20.7628x; 1.5018x over previous
//
#include <hip/hip_runtime.h>

#define DEVINL __device__ __forceinline__

typedef _Float16 f16_t;
typedef _Float16 f16x8 __attribute__((ext_vector_type(8)));
typedef float    f32x4 __attribute__((ext_vector_type(4)));
typedef unsigned long long u64;

static constexpr int SEQ  = 512;   // sequence length
static constexpr int BT   = 16;    // batch rows per block (= MFMA M)
static constexpr int NW   = 8;     // waves per block
static constexpr int RING = 128;   // ring capacity (steps)

// f16-element offsets of the three layer-boundary streams in d_ws
static constexpr size_t S0_OFF = 0;                          // L0->L1: 64*128*2048
static constexpr size_t S1_OFF = (size_t)64 * RING * 2048;   // L1->L2
static constexpr size_t S2_OFF = S1_OFF * 2;                 // L2->L3: 64*128*1024
static constexpr size_t FLAG_OFF_B = 88080384;               // byte offset of flags

DEVINL f32x4 mfma16(f16x8 a, f16x8 b, f32x4 c) {
  return __builtin_amdgcn_mfma_f32_16x16x32_f16(a, b, c, 0, 0, 0);
}

// LDS-only barrier: never drain vmcnt inside the step loop
DEVINL void sync_raw() {
  asm volatile("s_waitcnt lgkmcnt(0)" ::: "memory");
  __builtin_amdgcn_s_barrier();
  asm volatile("" ::: "memory");
}
DEVINL void sync_full() {
  asm volatile("s_waitcnt vmcnt(0) lgkmcnt(0)" ::: "memory");
  __builtin_amdgcn_s_barrier();
  asm volatile("" ::: "memory");
}

// ---- flags ----
DEVINL int  ld_flag(const int* p) { return __hip_atomic_load(p, __ATOMIC_RELAXED, __HIP_MEMORY_SCOPE_AGENT); }
DEVINL void st_flag(int* p, int v) { __hip_atomic_store(p, v, __ATOMIC_RELAXED, __HIP_MEMORY_SCOPE_AGENT); }
DEVINL void wait_ge(const int* p, int tgt) {
  while (ld_flag(p) < tgt) __builtin_amdgcn_s_sleep(2);
}

// ---- hot-loop data path: plain cache-bypassing asm ops (MALL-coherent) ----
DEVINL void gl_load16_coh(const f16_t* p, f16x8& r) {
  asm volatile("global_load_dwordx4 %0, %1, off sc0 sc1"
               : "=&v"(r) : "v"(p) : "memory");
}
DEVINL void gl_load32_f32(const float* p, f32x4& a, f32x4& b) {  // cached (immutable input)
  asm volatile("global_load_dwordx4 %0, %2, off\n\t"
               "global_load_dwordx4 %1, %2, off offset:16"
               : "=&v"(a), "=&v"(b) : "v"(p) : "memory");
}
DEVINL void gl_store8_coh(void* p, u64 v) {
  asm volatile("global_store_dwordx2 %0, %1, off sc0 sc1"
               :: "v"(p), "v"(v) : "memory");
}

// One pipeline stage: layer l for one 16-row batch tile, all 512 steps.
//
// Drain-free publish protocol: each step is ordered {h-store FIRST, then
// x-load issue}. The per-step counted wait vmcnt(NLOAD+1) therefore leaves
// only {this step's NLOAD loads + this step's store} outstanding, retiring
// (per wave) every store >= 2 steps old. At a chunk boundary t0 this holds
// for ALL waves (each executed the same wait before the last barrier), so
// tid0 may publish P = t0-3 with NO vmcnt(0) drain. Publishes every 2 steps.
template<int LIN, int H, int XMODE, bool PROD, bool CONS, bool LAST>
DEVINL void run_layer(const float* __restrict__ wih, const float* __restrict__ whh,
                      const float* __restrict__ bih, const float* __restrict__ bhh,
                      const float* __restrict__ x0,
                      const f16_t* __restrict__ sin_, f16_t* __restrict__ sout_,
                      const int* prog_up, int* cons_self,
                      int* prog_self, const int* cons_down,
                      int b0, f16_t* hbA, f16_t* hbB, float* h_fin)
{
  constexpr int H16   = H/16;
  constexpr int KX    = (XMODE==0) ? 1 : LIN/32;
  constexpr int KH    = H/32;
  constexpr int SLI   = 16*LIN;               // input slot elems (XMODE1)
  constexpr int SLO   = 16*H;                 // output slot elems
  constexpr int NLOAD = (XMODE==0) ? 2 : KX;  // asm load ops per step

  const int tid = (int)threadIdx.x;
  const int wv = tid >> 6, ln = tid & 63, lr = ln & 15, lg = ln >> 4;
  const bool act = (wv < H16);
  const int j = wv*16 + lr;                    // this lane's hidden col

  // ---- weight B-fragments: wf[gate][kt], lane holds col n=g*H+j, k=kt*32+lg*8+i ----
  f16x8 wf[4][KX+KH];
  float bias4[4];
  if (act) {
    #pragma unroll
    for (int g = 0; g < 4; ++g) {
      const int n = g*H + j;
      bias4[g] = bih[n] + bhh[n];
      #pragma unroll
      for (int kt = 0; kt < KX; ++kt)
        #pragma unroll
        for (int i = 0; i < 8; ++i) {
          const int k = kt*32 + lg*8 + i;
          wf[g][kt][i] = (f16_t)((k < LIN) ? wih[n*LIN + k] : 0.0f);  // L0 pads 8->32
        }
      #pragma unroll
      for (int kt = 0; kt < KH; ++kt)
        #pragma unroll
        for (int i = 0; i < 8; ++i)
          wf[g][KX+kt][i] = (f16_t)whh[n*H + kt*32 + lg*8 + i];
    }
  }

  for (int z = tid; z < BT*H; z += NW*64) { hbA[z] = (f16_t)0.0f; hbB[z] = (f16_t)0.0f; }
  float c4[4] = {0.0f, 0.0f, 0.0f, 0.0f};

  auto issue_loads = [&](int t, f16x8 (&xr)[KX], f32x4 (&pr)[2]) {
    if constexpr (XMODE == 0) {
      const float* p = x0 + ((size_t)(b0+lr)*SEQ + t)*8;
      gl_load32_f32(p, pr[0], pr[1]);
    } else {
      const f16_t* base = sin_ + (size_t)(t & (RING-1))*SLI + lr*LIN;
      #pragma unroll
      for (int kt = 0; kt < KX; ++kt) {
        const int chunk = ((kt*4 + lg) ^ (lr & 7)) * 8;    // swizzle folded in
        gl_load16_coh(base + chunk, xr[kt]);
      }
    }
  };

  // ---- initial consumer gate: covers prologue + first prefetches (x<=3) ----
  int fl_up = 0, fl_dn = 0;
  if constexpr (CONS) { wait_ge(prog_up, 7); fl_up = ld_flag(prog_up); }

  // ---- prologue: accA = bias + x_0 path; then issue loads for x_1 ----
  f32x4 accA[4], accB[4];
  f16x8 xA[KX], xB[KX];
  f32x4 pA[2], pB[2];
  if (act) {
    f16x8 x0f[KX]; f32x4 p0[2];
    issue_loads(0, x0f, p0);
    asm volatile("s_waitcnt vmcnt(0)" ::: "memory");
    __builtin_amdgcn_sched_barrier(0);
    #pragma unroll
    for (int g = 0; g < 4; ++g) {
      f32x4 a = {bias4[g], bias4[g], bias4[g], bias4[g]};
      accA[g] = a;
    }
    if constexpr (XMODE == 0) {
      f16x8 xf;
      #pragma unroll
      for (int i = 0; i < 8; ++i) {
        const float v = (lg == 0) ? ((i < 4) ? p0[0][i] : p0[1][i-4]) : 0.0f;
        xf[i] = (f16_t)v;
      }
      #pragma unroll
      for (int g = 0; g < 4; ++g) accA[g] = mfma16(xf, wf[g][0], accA[g]);
    } else {
      #pragma unroll
      for (int kt = 0; kt < KX; ++kt)
        #pragma unroll
        for (int g = 0; g < 4; ++g) accA[g] = mfma16(x0f[kt], wf[g][kt], accA[g]);
    }
    issue_loads(1, xA, pA);
  }
  __syncthreads();

  constexpr float K1 = 1.442695040888963f;   // log2(e)
  constexpr float K2 = 2.885390081777927f;   // 2*log2(e)

  auto step = [&](int t, f32x4 (&ac)[4], f32x4 (&an)[4],
                  f16x8 (&xc)[KX], f32x4 (&pc)[2],
                  f16x8 (&xn)[KX], f32x4 (&pn)[2],
                  f16_t* hr, f16_t* hw) {
    if (act) {
      // ph1: stream-copy h(t-1) FIRST (store older than this step's loads)
      if constexpr (PROD) {
        if (t >= 1) {
          const u64 v = *(const u64*)(hr + (size_t)tid*4);
          gl_store8_coh((u64*)(sout_ + (size_t)((t-1) & (RING-1))*SLO) + tid, v);
        }
      }
      // ph2: issue x prefetch for t+2
      const int tf = (t+2 < SEQ) ? t+2 : SEQ-1;
      issue_loads(tf, xn, pn);
      // ph3: h-path MFMAs (LDS only)
      #pragma unroll
      for (int kt = 0; kt < KH; ++kt) {
        const int chunk = ((kt*4 + lg) ^ (lr & 7)) * 8;
        const f16x8 ah = *(const f16x8*)&hr[lr*H + chunk];
        #pragma unroll
        for (int g = 0; g < 4; ++g) ac[g] = mfma16(ah, wf[g][KX+kt], ac[g]);
      }
      // ph4: counted wait — retires prev-step loads AND stores >=2 steps old
      if constexpr (PROD) {
        if (t >= 1) { asm volatile("s_waitcnt vmcnt(%0)" :: "i"(NLOAD+1) : "memory"); }
        else        { asm volatile("s_waitcnt vmcnt(%0)" :: "i"(NLOAD)   : "memory"); }
      } else {
        asm volatile("s_waitcnt vmcnt(%0)" :: "i"(NLOAD) : "memory");
      }
      __builtin_amdgcn_sched_barrier(0);
      // ph5: next-step acc: bias + x_{t+1} path
      #pragma unroll
      for (int g = 0; g < 4; ++g) {
        f32x4 a = {bias4[g], bias4[g], bias4[g], bias4[g]};
        an[g] = a;
      }
      if constexpr (XMODE == 0) {
        f16x8 xf;
        #pragma unroll
        for (int i = 0; i < 8; ++i) {
          const float v = (lg == 0) ? ((i < 4) ? pc[0][i] : pc[1][i-4]) : 0.0f;
          xf[i] = (f16_t)v;
        }
        #pragma unroll
        for (int g = 0; g < 4; ++g) an[g] = mfma16(xf, wf[g][0], an[g]);
      } else {
        #pragma unroll
        for (int kt = 0; kt < KX; ++kt)
          #pragma unroll
          for (int g = 0; g < 4; ++g) an[g] = mfma16(xc[kt], wf[g][kt], an[g]);
      }
      // ph6: gates — 5 exp2 + 2 rcp; one-sided clamps only where -inf -> NaN
      #pragma unroll
      for (int r = 0; r < 4; ++r) {
        const int b = lg*4 + r;
        const float ei = __builtin_amdgcn_exp2f(-K1*ac[0][r]);
        const float ef = __builtin_amdgcn_exp2f(-K1*ac[1][r]);
        const float eg = __builtin_amdgcn_exp2f(-K2*fmaxf(ac[2][r], -42.f));
        const float eo = __builtin_amdgcn_exp2f(-K1*ac[3][r]);
        const float pig = (1.f + ei)*(1.f + eg);
        // cv = c/(1+ef) + (1-eg)/pig  via common denominator (one rcp)
        const float cv = (c4[r]*pig + (1.f - eg)*(1.f + ef))
                         * __builtin_amdgcn_rcpf((1.f + ef)*pig);
        c4[r] = cv;
        const float ec = __builtin_amdgcn_exp2f(-K2*fmaxf(cv, -42.f));
        const float h  = (1.f - ec) * __builtin_amdgcn_rcpf((1.f + eo)*(1.f + ec));
        hw[b*H + (j ^ ((b & 7) << 3))] = (f16_t)h;
        if constexpr (LAST) if (t == SEQ-1) h_fin[b*64 + j] = h;
      }
    }
    sync_raw();   // ph7
  };

  // 2-step chunks; drain-free publishes each boundary
  for (int t0 = 0; t0 < SEQ; t0 += 2) {
    if (t0 > 0) {
      if constexpr (PROD) if (tid == 0) st_flag(prog_self, t0 - 3);
      if constexpr (CONS) {
        if ((t0 & 15) == 0 && tid == 0) st_flag(cons_self, t0 - 1);
        const int tgt = (t0+3 < SEQ-1) ? t0+3 : SEQ-1;
        if (fl_up < tgt) wait_ge(prog_up, tgt);
        fl_up = ld_flag(prog_up);                 // prefetch next boundary
      }
      if constexpr (PROD) {
        if (t0 >= 112) {                          // ring slot-reuse safety
          const int tgt2 = t0 - 112;
          if (fl_dn < tgt2) wait_ge(cons_down, tgt2);
          fl_dn = ld_flag(cons_down);
        }
      }
    }
    step(t0,   accA, accB, xA, pA, xB, pB, hbB, hbA);
    step(t0+1, accB, accA, xB, pB, xA, pA, hbA, hbB);
  }

  // EPILOGUE: stream h(SEQ-1) (loop's shifted copy never emits it). t=511 odd -> hbB.
  if constexpr (PROD) {
    if (act) {
      const u64 v = *(const u64*)(hbB + (size_t)tid*4);
      gl_store8_coh((u64*)(sout_ + (size_t)((SEQ-1) & (RING-1))*SLO) + tid, v);
    }
  }
  sync_full();
  if (tid == 0) {
    if constexpr (PROD) st_flag(prog_self, SEQ);
    if constexpr (CONS) st_flag(cons_self, SEQ);
  }
}

extern "C" __global__ void lstm_init_flags(int* f) {
  const int i = (int)blockIdx.x * (int)blockDim.x + (int)threadIdx.x;
  if (i < 6144) f[i] = 0;
}

// 256 blocks: (bid&3)=layer, (bid>>2)=batch tile. One block/CU -> all resident.
extern "C" __global__ __launch_bounds__(512, 2)
void lstm_pipe(const float* __restrict__ xin,
  const float* w0i, const float* w0h, const float* b0i, const float* b0h,
  const float* w1i, const float* w1h, const float* b1i, const float* b1h,
  const float* w2i, const float* w2h, const float* b2i, const float* b2h,
  const float* w3i, const float* w3h, const float* b3i, const float* b3h,
  const float* __restrict__ lw, const float* __restrict__ lb,
  float* __restrict__ out, f16_t* ws16, int* flags)
{
  __shared__ __align__(16) f16_t hbuf0[BT*128];
  __shared__ __align__(16) f16_t hbuf1[BT*128];
  __shared__ float h_fin[BT*64];

  const int bid = (int)blockIdx.x;
  const int l = bid & 3, bt = bid >> 2, b0 = bt * BT;
  int* progf = flags;
  int* consf = flags + 3*64*16;
  int* P0 = progf + (0*64+bt)*16; int* C0 = consf + (0*64+bt)*16;
  int* P1 = progf + (1*64+bt)*16; int* C1 = consf + (1*64+bt)*16;
  int* P2 = progf + (2*64+bt)*16; int* C2 = consf + (2*64+bt)*16;

  f16_t* s0 = ws16 + S0_OFF + (size_t)bt * RING * 2048;
  f16_t* s1 = ws16 + S1_OFF + (size_t)bt * RING * 2048;
  f16_t* s2 = ws16 + S2_OFF + (size_t)bt * RING * 1024;

  if (l == 0) {
    run_layer<8,   128, 0, true,  false, false>(w0i,w0h,b0i,b0h, xin, nullptr, s0,
        nullptr, nullptr, P0, C0, b0, hbuf0, hbuf1, h_fin);
  } else if (l == 1) {
    run_layer<128, 128, 1, true,  true,  false>(w1i,w1h,b1i,b1h, nullptr, s0, s1,
        P0, C0, P1, C1, b0, hbuf0, hbuf1, h_fin);
  } else if (l == 2) {
    run_layer<128, 64,  1, true,  true,  false>(w2i,w2h,b2i,b2h, nullptr, s1, s2,
        P1, C1, P2, C2, b0, hbuf0, hbuf1, h_fin);
  } else {
    run_layer<64,  64,  1, false, true,  true >(w3i,w3h,b3i,b3h, nullptr, s2, nullptr,
        P2, C2, nullptr, nullptr, b0, hbuf0, hbuf1, h_fin);
    // final linear: out[b] = h_fin[b,:] . lw + lb
    const int wv = (int)threadIdx.x >> 6;
    const int ln = (int)threadIdx.x & 63;
    #pragma unroll
    for (int rr = 0; rr < 2; ++rr) {
      const int row = wv*2 + rr;
      float v = h_fin[row*64 + ln] * lw[ln];
      #pragma unroll
      for (int m = 32; m >= 1; m >>= 1) v += __shfl_xor(v, m, 64);
      if (ln == 0) out[b0 + row] = v + lb[0];
    }
  }
}

extern "C" void kernel_launch(void* const* d_in, const int* in_sizes, int n_in,
                              void* d_out, int out_size, void* d_ws, size_t ws_size,
                              hipStream_t stream) {
  const float* xin = (const float*)d_in[0];
  const float* w0i = (const float*)d_in[1];
  const float* w0h = (const float*)d_in[2];
  const float* b0i = (const float*)d_in[3];
  const float* b0h = (const float*)d_in[4];
  const float* w1i = (const float*)d_in[5];
  const float* w1h = (const float*)d_in[6];
  const float* b1i = (const float*)d_in[7];
  const float* b1h = (const float*)d_in[8];
  const float* w2i = (const float*)d_in[9];
  const float* w2h = (const float*)d_in[10];
  const float* b2i = (const float*)d_in[11];
  const float* b2h = (const float*)d_in[12];
  const float* w3i = (const float*)d_in[13];
  const float* w3h = (const float*)d_in[14];
  const float* b3i = (const float*)d_in[15];
  const float* b3h = (const float*)d_in[16];
  const float* lw  = (const float*)d_in[17];
  const float* lb  = (const float*)d_in[18];
  float* out = (float*)d_out;

  f16_t* ws16 = (f16_t*)d_ws;                       // ~80 MB streams
  int* flags  = (int*)((char*)d_ws + FLAG_OFF_B);   // 24 KB flags

  lstm_init_flags<<<12, 512, 0, stream>>>(flags);   // re-zero per launch (replay-safe)
  lstm_pipe<<<256, 512, 0, stream>>>(xin,
      w0i,w0h,b0i,b0h, w1i,w1h,b1i,b1h, w2i,w2h,b2i,b2h, w3i,w3h,b3i,b3h,
      lw, lb, out, ws16, flags);
}

// Round 9
// 648.342 us; speedup vs baseline: 24.2274x; 1.1669x over previous
//
#include <hip/hip_runtime.h>

#define DEVINL __device__ __forceinline__

typedef _Float16 f16_t;
typedef _Float16 f16x8 __attribute__((ext_vector_type(8)));
typedef float    f32x4 __attribute__((ext_vector_type(4)));
typedef unsigned long long u64;

static constexpr int SEQ  = 512;   // sequence length
static constexpr int BT   = 16;    // batch rows per block (= MFMA M)
static constexpr int NW   = 8;     // waves per block
static constexpr int RING = 128;   // ring capacity (steps)

// f16-element offsets of the three layer-boundary streams in d_ws
static constexpr size_t S0_OFF = 0;                          // L0->L1: 64*128*2048
static constexpr size_t S1_OFF = (size_t)64 * RING * 2048;   // L1->L2
static constexpr size_t S2_OFF = S1_OFF * 2;                 // L2->L3: 64*128*1024
static constexpr size_t FLAG_OFF_B = 88080384;               // byte offset of flags

DEVINL f32x4 mfma16(f16x8 a, f16x8 b, f32x4 c) {
  return __builtin_amdgcn_mfma_f32_16x16x32_f16(a, b, c, 0, 0, 0);
}

// LDS-only barrier: never drain vmcnt inside the step loop
DEVINL void sync_raw() {
  asm volatile("s_waitcnt lgkmcnt(0)" ::: "memory");
  __builtin_amdgcn_s_barrier();
  asm volatile("" ::: "memory");
}
DEVINL void sync_full() {
  asm volatile("s_waitcnt vmcnt(0) lgkmcnt(0)" ::: "memory");
  __builtin_amdgcn_s_barrier();
  asm volatile("" ::: "memory");
}

// ---- flags ----
DEVINL int  ld_flag(const int* p) { return __hip_atomic_load(p, __ATOMIC_RELAXED, __HIP_MEMORY_SCOPE_AGENT); }
DEVINL void st_flag(int* p, int v) { __hip_atomic_store(p, v, __ATOMIC_RELAXED, __HIP_MEMORY_SCOPE_AGENT); }
DEVINL void wait_ge(const int* p, int tgt) {
  while (ld_flag(p) < tgt) __builtin_amdgcn_s_sleep(2);
}

// ---- hot-loop data path: plain cache-bypassing asm ops (MALL-coherent) ----
DEVINL void gl_load16_coh(const f16_t* p, f16x8& r) {
  asm volatile("global_load_dwordx4 %0, %1, off sc0 sc1"
               : "=&v"(r) : "v"(p) : "memory");
}
DEVINL void gl_load32_f32(const float* p, f32x4& a, f32x4& b) {  // cached (immutable input)
  asm volatile("global_load_dwordx4 %0, %2, off\n\t"
               "global_load_dwordx4 %1, %2, off offset:16"
               : "=&v"(a), "=&v"(b) : "v"(p) : "memory");
}
DEVINL void gl_store8_coh(void* p, u64 v) {
  asm volatile("global_store_dwordx2 %0, %1, off sc0 sc1"
               :: "v"(p), "v"(v) : "memory");
}

// One pipeline stage: layer l for one 16-row batch tile, all 512 steps.
//
// R9 step order (critical-path-minimal):
//   ph1 h-store(t-1)  ph2 x-load issue(t+2)  ph3 h-MFMAs  ph4 gates+h-write
//   ph5 counted vmcnt ph6 x-MFMAs(t+1)       ph7 barrier
// Gates depend only on the h-path accumulators, so the vmcnt wait (for x(t+1),
// issued at t-1) now has cover = one full step INCLUDING the gate phase
// (~1600cy >> MALL latency), and the wait + x-MFMA issue are off the
// h(t)->h(t+1) serial chain.
//
// Drain-free publish: step order keeps the h-store the OLDEST VMEM op of the
// step, so vmcnt(NLOAD+1) retires every store >=2 steps old per wave; at a
// chunk boundary all waves have executed that wait behind the barrier ->
// tid0 publishes P = t0-3 with no drain.
template<int LIN, int H, int XMODE, bool PROD, bool CONS, bool LAST>
DEVINL void run_layer(const float* __restrict__ wih, const float* __restrict__ whh,
                      const float* __restrict__ bih, const float* __restrict__ bhh,
                      const float* __restrict__ x0,
                      const f16_t* __restrict__ sin_, f16_t* __restrict__ sout_,
                      const int* prog_up, int* cons_self,
                      int* prog_self, const int* cons_down,
                      int b0, f16_t* hbA, f16_t* hbB, float* h_fin)
{
  constexpr int H16   = H/16;
  constexpr int KX    = (XMODE==0) ? 1 : LIN/32;
  constexpr int KH    = H/32;
  constexpr int SLI   = 16*LIN;               // input slot elems (XMODE1)
  constexpr int SLO   = 16*H;                 // output slot elems
  constexpr int NLOAD = (XMODE==0) ? 2 : KX;  // asm load ops per step

  const int tid = (int)threadIdx.x;
  const int wv = tid >> 6, ln = tid & 63, lr = ln & 15, lg = ln >> 4;
  const bool act = (wv < H16);
  const int j = wv*16 + lr;                    // this lane's hidden col

  // ---- weight B-fragments: wf[gate][kt], lane holds col n=g*H+j, k=kt*32+lg*8+i ----
  f16x8 wf[4][KX+KH];
  float bias4[4];
  if (act) {
    #pragma unroll
    for (int g = 0; g < 4; ++g) {
      const int n = g*H + j;
      bias4[g] = bih[n] + bhh[n];
      #pragma unroll
      for (int kt = 0; kt < KX; ++kt)
        #pragma unroll
        for (int i = 0; i < 8; ++i) {
          const int k = kt*32 + lg*8 + i;
          wf[g][kt][i] = (f16_t)((k < LIN) ? wih[n*LIN + k] : 0.0f);  // L0 pads 8->32
        }
      #pragma unroll
      for (int kt = 0; kt < KH; ++kt)
        #pragma unroll
        for (int i = 0; i < 8; ++i)
          wf[g][KX+kt][i] = (f16_t)whh[n*H + kt*32 + lg*8 + i];
    }
  }

  for (int z = tid; z < BT*H; z += NW*64) { hbA[z] = (f16_t)0.0f; hbB[z] = (f16_t)0.0f; }
  float c4[4] = {0.0f, 0.0f, 0.0f, 0.0f};

  auto issue_loads = [&](int t, f16x8 (&xr)[KX], f32x4 (&pr)[2]) {
    if constexpr (XMODE == 0) {
      const float* p = x0 + ((size_t)(b0+lr)*SEQ + t)*8;
      gl_load32_f32(p, pr[0], pr[1]);
    } else {
      const f16_t* base = sin_ + (size_t)(t & (RING-1))*SLI + lr*LIN;
      #pragma unroll
      for (int kt = 0; kt < KX; ++kt) {
        const int chunk = ((kt*4 + lg) ^ (lr & 7)) * 8;    // swizzle folded in
        gl_load16_coh(base + chunk, xr[kt]);
      }
    }
  };

  // ---- initial consumer gate: covers prologue + first prefetches (x<=3) ----
  int fl_up = 0, fl_dn = 0;
  if constexpr (CONS) { wait_ge(prog_up, 7); fl_up = ld_flag(prog_up); }

  // ---- prologue: accA = bias + x_0 path; then issue loads for x_1 ----
  f32x4 accA[4], accB[4];
  f16x8 xA[KX], xB[KX];
  f32x4 pA[2], pB[2];
  if (act) {
    f16x8 x0f[KX]; f32x4 p0[2];
    issue_loads(0, x0f, p0);
    asm volatile("s_waitcnt vmcnt(0)" ::: "memory");
    __builtin_amdgcn_sched_barrier(0);
    #pragma unroll
    for (int g = 0; g < 4; ++g) {
      f32x4 a = {bias4[g], bias4[g], bias4[g], bias4[g]};
      accA[g] = a;
    }
    if constexpr (XMODE == 0) {
      f16x8 xf;
      #pragma unroll
      for (int i = 0; i < 8; ++i) {
        const float v = (lg == 0) ? ((i < 4) ? p0[0][i] : p0[1][i-4]) : 0.0f;
        xf[i] = (f16_t)v;
      }
      #pragma unroll
      for (int g = 0; g < 4; ++g) accA[g] = mfma16(xf, wf[g][0], accA[g]);
    } else {
      #pragma unroll
      for (int kt = 0; kt < KX; ++kt)
        #pragma unroll
        for (int g = 0; g < 4; ++g) accA[g] = mfma16(x0f[kt], wf[g][kt], accA[g]);
    }
    issue_loads(1, xA, pA);
  }
  __syncthreads();

  constexpr float K1 = 1.442695040888963f;   // log2(e)
  constexpr float K2 = 2.885390081777927f;   // 2*log2(e)

  auto step = [&](int t, f32x4 (&ac)[4], f32x4 (&an)[4],
                  f16x8 (&xc)[KX], f32x4 (&pc)[2],
                  f16x8 (&xn)[KX], f32x4 (&pn)[2],
                  f16_t* hr, f16_t* hw) {
    if (act) {
      // ph1: stream-copy h(t-1) FIRST (store stays oldest VMEM of the step)
      if constexpr (PROD) {
        if (t >= 1) {
          const u64 v = *(const u64*)(hr + (size_t)tid*4);
          gl_store8_coh((u64*)(sout_ + (size_t)((t-1) & (RING-1))*SLO) + tid, v);
        }
      }
      // ph2: issue x prefetch for t+2
      const int tf = (t+2 < SEQ) ? t+2 : SEQ-1;
      issue_loads(tf, xn, pn);
      // ph3: h-path MFMAs (LDS only)
      #pragma unroll
      for (int kt = 0; kt < KH; ++kt) {
        const int chunk = ((kt*4 + lg) ^ (lr & 7)) * 8;
        const f16x8 ah = *(const f16x8*)&hr[lr*H + chunk];
        #pragma unroll
        for (int g = 0; g < 4; ++g) ac[g] = mfma16(ah, wf[g][KX+kt], ac[g]);
      }
      // ph4: gates (depend only on ac) — 5 exp2 + 2 rcp; write h(t) to LDS
      #pragma unroll
      for (int r = 0; r < 4; ++r) {
        const int b = lg*4 + r;
        const float ei = __builtin_amdgcn_exp2f(-K1*ac[0][r]);
        const float ef = __builtin_amdgcn_exp2f(-K1*ac[1][r]);
        const float eg = __builtin_amdgcn_exp2f(-K2*fmaxf(ac[2][r], -42.f));
        const float eo = __builtin_amdgcn_exp2f(-K1*ac[3][r]);
        const float pig = (1.f + ei)*(1.f + eg);
        // cv = c/(1+ef) + (1-eg)/pig  via common denominator (one rcp)
        const float cv = (c4[r]*pig + (1.f - eg)*(1.f + ef))
                         * __builtin_amdgcn_rcpf((1.f + ef)*pig);
        c4[r] = cv;
        const float ec = __builtin_amdgcn_exp2f(-K2*fmaxf(cv, -42.f));
        const float h  = (1.f - ec) * __builtin_amdgcn_rcpf((1.f + eo)*(1.f + ec));
        hw[b*H + (j ^ ((b & 7) << 3))] = (f16_t)h;
        if constexpr (LAST) if (t == SEQ-1) h_fin[b*64 + j] = h;
      }
      // ph5: counted wait — retires x(t+1) loads (issued t-1) + stores >=2 old
      if constexpr (PROD) {
        if (t >= 1) { asm volatile("s_waitcnt vmcnt(%0)" :: "i"(NLOAD+1) : "memory"); }
        else        { asm volatile("s_waitcnt vmcnt(%0)" :: "i"(NLOAD)   : "memory"); }
      } else {
        asm volatile("s_waitcnt vmcnt(%0)" :: "i"(NLOAD) : "memory");
      }
      __builtin_amdgcn_sched_barrier(0);
      // ph6: next-step acc: bias + x_{t+1} path (off the h critical chain)
      #pragma unroll
      for (int g = 0; g < 4; ++g) {
        f32x4 a = {bias4[g], bias4[g], bias4[g], bias4[g]};
        an[g] = a;
      }
      if constexpr (XMODE == 0) {
        f16x8 xf;
        #pragma unroll
        for (int i = 0; i < 8; ++i) {
          const float v = (lg == 0) ? ((i < 4) ? pc[0][i] : pc[1][i-4]) : 0.0f;
          xf[i] = (f16_t)v;
        }
        #pragma unroll
        for (int g = 0; g < 4; ++g) an[g] = mfma16(xf, wf[g][0], an[g]);
      } else {
        #pragma unroll
        for (int kt = 0; kt < KX; ++kt)
          #pragma unroll
          for (int g = 0; g < 4; ++g) an[g] = mfma16(xc[kt], wf[g][kt], an[g]);
      }
    }
    sync_raw();   // ph7
  };

  // 2-step chunks; drain-free publishes each boundary
  for (int t0 = 0; t0 < SEQ; t0 += 2) {
    if (t0 > 0) {
      if constexpr (PROD) if (tid == 0) st_flag(prog_self, t0 - 3);
      if constexpr (CONS) {
        if ((t0 & 15) == 0 && tid == 0) st_flag(cons_self, t0 - 1);
        const int tgt = (t0+3 < SEQ-1) ? t0+3 : SEQ-1;
        if (fl_up < tgt) wait_ge(prog_up, tgt);
        fl_up = ld_flag(prog_up);                 // prefetch next boundary
      }
      if constexpr (PROD) {
        if (t0 >= 112) {                          // ring slot-reuse safety
          const int tgt2 = t0 - 112;
          if (fl_dn < tgt2) wait_ge(cons_down, tgt2);
          fl_dn = ld_flag(cons_down);
        }
      }
    }
    step(t0,   accA, accB, xA, pA, xB, pB, hbB, hbA);
    step(t0+1, accB, accA, xB, pB, xA, pA, hbA, hbB);
  }

  // EPILOGUE: stream h(SEQ-1) (loop's shifted copy never emits it). t=511 odd -> hbB.
  if constexpr (PROD) {
    if (act) {
      const u64 v = *(const u64*)(hbB + (size_t)tid*4);
      gl_store8_coh((u64*)(sout_ + (size_t)((SEQ-1) & (RING-1))*SLO) + tid, v);
    }
  }
  sync_full();
  if (tid == 0) {
    if constexpr (PROD) st_flag(prog_self, SEQ);
    if constexpr (CONS) st_flag(cons_self, SEQ);
  }
}

extern "C" __global__ void lstm_init_flags(int* f) {
  const int i = (int)blockIdx.x * (int)blockDim.x + (int)threadIdx.x;
  if (i < 6144) f[i] = 0;
}

// 256 blocks: (bid&3)=layer, (bid>>2)=batch tile. One block/CU -> all resident.
extern "C" __global__ __launch_bounds__(512, 2)
void lstm_pipe(const float* __restrict__ xin,
  const float* w0i, const float* w0h, const float* b0i, const float* b0h,
  const float* w1i, const float* w1h, const float* b1i, const float* b1h,
  const float* w2i, const float* w2h, const float* b2i, const float* b2h,
  const float* w3i, const float* w3h, const float* b3i, const float* b3h,
  const float* __restrict__ lw, const float* __restrict__ lb,
  float* __restrict__ out, f16_t* ws16, int* flags)
{
  __shared__ __align__(16) f16_t hbuf0[BT*128];
  __shared__ __align__(16) f16_t hbuf1[BT*128];
  __shared__ float h_fin[BT*64];

  const int bid = (int)blockIdx.x;
  const int l = bid & 3, bt = bid >> 2, b0 = bt * BT;
  int* progf = flags;
  int* consf = flags + 3*64*16;
  int* P0 = progf + (0*64+bt)*16; int* C0 = consf + (0*64+bt)*16;
  int* P1 = progf + (1*64+bt)*16; int* C1 = consf + (1*64+bt)*16;
  int* P2 = progf + (2*64+bt)*16; int* C2 = consf + (2*64+bt)*16;

  f16_t* s0 = ws16 + S0_OFF + (size_t)bt * RING * 2048;
  f16_t* s1 = ws16 + S1_OFF + (size_t)bt * RING * 2048;
  f16_t* s2 = ws16 + S2_OFF + (size_t)bt * RING * 1024;

  if (l == 0) {
    run_layer<8,   128, 0, true,  false, false>(w0i,w0h,b0i,b0h, xin, nullptr, s0,
        nullptr, nullptr, P0, C0, b0, hbuf0, hbuf1, h_fin);
  } else if (l == 1) {
    run_layer<128, 128, 1, true,  true,  false>(w1i,w1h,b1i,b1h, nullptr, s0, s1,
        P0, C0, P1, C1, b0, hbuf0, hbuf1, h_fin);
  } else if (l == 2) {
    run_layer<128, 64,  1, true,  true,  false>(w2i,w2h,b2i,b2h, nullptr, s1, s2,
        P1, C1, P2, C2, b0, hbuf0, hbuf1, h_fin);
  } else {
    run_layer<64,  64,  1, false, true,  true >(w3i,w3h,b3i,b3h, nullptr, s2, nullptr,
        P2, C2, nullptr, nullptr, b0, hbuf0, hbuf1, h_fin);
    // final linear: out[b] = h_fin[b,:] . lw + lb
    const int wv = (int)threadIdx.x >> 6;
    const int ln = (int)threadIdx.x & 63;
    #pragma unroll
    for (int rr = 0; rr < 2; ++rr) {
      const int row = wv*2 + rr;
      float v = h_fin[row*64 + ln] * lw[ln];
      #pragma unroll
      for (int m = 32; m >= 1; m >>= 1) v += __shfl_xor(v, m, 64);
      if (ln == 0) out[b0 + row] = v + lb[0];
    }
  }
}

extern "C" void kernel_launch(void* const* d_in, const int* in_sizes, int n_in,
                              void* d_out, int out_size, void* d_ws, size_t ws_size,
                              hipStream_t stream) {
  const float* xin = (const float*)d_in[0];
  const float* w0i = (const float*)d_in[1];
  const float* w0h = (const float*)d_in[2];
  const float* b0i = (const float*)d_in[3];
  const float* b0h = (const float*)d_in[4];
  const float* w1i = (const float*)d_in[5];
  const float* w1h = (const float*)d_in[6];
  const float* b1i = (const float*)d_in[7];
  const float* b1h = (const float*)d_in[8];
  const float* w2i = (const float*)d_in[9];
  const float* w2h = (const float*)d_in[10];
  const float* b2i = (const float*)d_in[11];
  const float* b2h = (const float*)d_in[12];
  const float* w3i = (const float*)d_in[13];
  const float* w3h = (const float*)d_in[14];
  const float* b3i = (const float*)d_in[15];
  const float* b3h = (const float*)d_in[16];
  const float* lw  = (const float*)d_in[17];
  const float* lb  = (const float*)d_in[18];
  float* out = (float*)d_out;

  f16_t* ws16 = (f16_t*)d_ws;                       // ~80 MB streams
  int* flags  = (int*)((char*)d_ws + FLAG_OFF_B);   // 24 KB flags

  lstm_init_flags<<<12, 512, 0, stream>>>(flags);   // re-zero per launch (replay-safe)
  lstm_pipe<<<256, 512, 0, stream>>>(xin,
      w0i,w0h,b0i,b0h, w1i,w1h,b1i,b1h, w2i,w2h,b2i,b2h, w3i,w3h,b3i,b3h,
      lw, lb, out, ws16, flags);
}